// Round 10
// baseline (9614.432 us; speedup 1.0000x reference)
//
#include <hip/hip_runtime.h>
#include <math.h>

// Model: 10 parallel LSTMs -> MI-LSTM w/ stream attention -> linear head.
// All f32 (no fp32-input MFMA on CDNA4; accuracy threshold requires f32).
//
#define SS 10
#define TT 256
#define BB 128
#define HH 128
#define II 128
#define G4 512     // 4H
#define ZK 256     // I + H (fused [x|h] contraction)
#define NCOL 2944  // phase-D fused weight columns: Ui(1280)|Uc(1280)|Uf(128)|Uo(128)|Wa(128)
#define NBLK 92    // cooperative blocks: 92 x 32 cols = 2944

#define SZ_W2T   (SS*ZK*G4)        // 1,310,720
#define SZ_BIAS2 (SS*G4)           // 5,120
#define SZ_UBIG  (HH*NCOL)         // 376,832
#define SZ_TILDE (SS*TT*BB*HH)     // 41,943,040
#define SZ_X     (TT*SS*BB*HH)     // 41,943,040
#define SZ_XFO   (TT*BB*HH)        // 4,194,304

#define OFF_W2T   0
#define OFF_BIAS2 (OFF_W2T + SZ_W2T)
#define OFF_UBIG  (OFF_BIAS2 + SZ_BIAS2)
#define OFF_TILDE (OFF_UBIG + SZ_UBIG)
#define OFF_XI    (OFF_TILDE + SZ_TILDE)
#define OFF_XC    (OFF_XI + SZ_X)
#define OFF_XF    (OFF_XC + SZ_X)
#define OFF_XO    (OFF_XF + SZ_XFO)
#define OFF_HT    (OFF_XO + SZ_XFO)
#define OFF_CT    (OFF_HT + BB*HH)
#define OFF_ACT   (OFF_CT + BB*HH)
#define OFF_CNT   (OFF_ACT + BB*NCOL)

__device__ __forceinline__ float sigf(float x){ return 1.0f/(1.0f+expf(-x)); }

// per-access coherent ops (sc0/sc1 path; no cache-wide wb/inv)
__device__ __forceinline__ float ald(const float* p){
  return __hip_atomic_load(p, __ATOMIC_RELAXED, __HIP_MEMORY_SCOPE_AGENT);
}
__device__ __forceinline__ void ast(float* p, float v){
  __hip_atomic_store(p, v, __ATOMIC_RELAXED, __HIP_MEMORY_SCOPE_AGENT);
}
__device__ __forceinline__ int aldi(const int* p){
  return __hip_atomic_load(p, __ATOMIC_RELAXED, __HIP_MEMORY_SCOPE_AGENT);
}
__device__ __forceinline__ void asti(int* p, int v){
  __hip_atomic_store(p, v, __ATOMIC_RELAXED, __HIP_MEMORY_SCOPE_AGENT);
}
// 16B coherent ops. ext_vector_type binds to a VGPR quad (HIP float4 is a struct, cannot).
typedef float f32x4v __attribute__((ext_vector_type(4)));
__device__ __forceinline__ void ast4(float* p, float a, float b, float c, float d){
  f32x4v w; w.x = a; w.y = b; w.z = c; w.w = d;
  asm volatile("global_store_dwordx4 %0, %1, off sc0 sc1" :: "v"(p), "v"(w) : "memory");
}
__device__ __forceinline__ f32x4v ald4(const float* p){
  f32x4v r;
  asm volatile("global_load_dwordx4 %0, %1, off sc0 sc1" : "=v"(r) : "v"(p) : "memory");
  return r;
}

// ---------------- prep: fused transposed LSTM weights (b128-friendly) ----------------
__global__ __launch_bounds__(256) void prep_w2t(const float* __restrict__ Wih, const float* __restrict__ Whh,
                                                const float* __restrict__ bih, const float* __restrict__ bhh,
                                                float* __restrict__ w2t, float* __restrict__ bias2){
  int idx = blockIdx.x*256 + threadIdx.x;
  if (idx < SZ_W2T){
    int q = idx & 3; int j = (idx >> 2) & 511; int kk4 = (idx >> 11) & 63; int s = idx >> 17;
    int kk = kk4*4 + q;
    float v = (kk < II) ? Wih[(s*G4 + j)*II + kk] : Whh[(s*G4 + j)*HH + (kk - II)];
    w2t[idx] = v;
  }
  if (idx < SZ_BIAS2) bias2[idx] = bih[idx] + bhh[idx];
}

__global__ __launch_bounds__(256) void prep_ubig(const float* __restrict__ Ui, const float* __restrict__ Uc,
                                                 const float* __restrict__ Uf, const float* __restrict__ Uo,
                                                 const float* __restrict__ Wa, float* __restrict__ ubig){
  int idx = blockIdx.x*256 + threadIdx.x;
  if (idx >= SZ_UBIG) return;
  int col = idx % NCOL; int h = idx / NCOL;
  float v;
  if (col < 1280){ int k = col >> 7, d = col & 127; v = Ui[(k*HH + h)*HH + d]; }
  else if (col < 2560){ int c2 = col - 1280; int k = c2 >> 7, d = c2 & 127; v = Uc[(k*HH + h)*HH + d]; }
  else if (col < 2688){ v = Uf[h*HH + (col - 2560)]; }
  else if (col < 2816){ v = Uo[h*HH + (col - 2688)]; }
  else               { v = Wa[h*HH + (col - 2816)]; }
  ubig[idx] = v;
}

// ---------------- phase B: fused 10x LSTM scan (8 rows/block, 160 blocks) ----------------
// 4-deep rolling weight prefetch: keeps ~4 L2 loads in flight so the kk4 loop
// is FMA-issue-bound instead of load-latency-bound.
__global__ __launch_bounds__(512) void lstm_scan(const float* __restrict__ feat, const float* __restrict__ w2t,
                                                 const float* __restrict__ bias2, float* __restrict__ tilde){
  int p = blockIdx.x;                 // 0..159
  int g = (p & 7) * 20 + (p >> 3);
  int s = g >> 4; int rb = g & 15; int b0 = rb * 8;
  int tid = threadIdx.x;
  __shared__ float z[8][ZK];
  __shared__ float gl[8][G4];
  const float* w2ts = w2t + (size_t)s*ZK*G4;
  const float* wb = w2ts + tid*4;
  float bj = bias2[s*G4 + tid];
  float c0 = 0.f, c1 = 0.f;
  {
    int q = tid*2; int r = q >> 7; int k = q & 127;
    z[r][128+k] = 0.f; z[r][128+k+1] = 0.f;
    const float* xrow = feat + ((s*TT + 0)*BB + (b0+r))*II;
    float2 xv = *(const float2*)(xrow + k);
    z[r][k] = xv.x; z[r][k+1] = xv.y;
  }
  __syncthreads();
  float4 wbuf[4];
  #pragma unroll
  for (int i = 0; i < 4; ++i) wbuf[i] = *(const float4*)(wb + i*2048);
  for (int t = 0; t < TT; ++t){
    float acc[8];
    #pragma unroll
    for (int r=0;r<8;++r) acc[r] = bj;
    for (int kk4 = 0; kk4 < 64; kk4 += 4){
      #pragma unroll
      for (int sfl = 0; sfl < 4; ++sfl){
        float4 wv = wbuf[sfl];
        wbuf[sfl] = *(const float4*)(wb + (((kk4 + 4 + sfl) & 63) * 2048));
        #pragma unroll
        for (int r=0;r<8;++r){
          float4 zv = *(const float4*)&z[r][(kk4+sfl)*4];
          acc[r] = fmaf(zv.w, wv.w, fmaf(zv.z, wv.z, fmaf(zv.y, wv.y, fmaf(zv.x, wv.x, acc[r]))));
        }
      }
    }
    int gtype = tid >> 7;
    #pragma unroll
    for (int r=0;r<8;++r){
      float v = acc[r];
      v = (gtype == 2) ? tanhf(v) : sigf(v);
      gl[r][tid] = v;
    }
    __syncthreads();
    {
      int q = tid*2; int r = q >> 7; int k = q & 127;
      float si0 = gl[r][k],     si1 = gl[r][k+1];
      float sf0 = gl[r][128+k], sf1 = gl[r][128+k+1];
      float tg0 = gl[r][256+k], tg1 = gl[r][256+k+1];
      float so0 = gl[r][384+k], so1 = gl[r][384+k+1];
      c0 = sf0*c0 + si0*tg0;
      c1 = sf1*c1 + si1*tg1;
      float h0 = so0*tanhf(c0), h1 = so1*tanhf(c1);
      z[r][128+k] = h0; z[r][128+k+1] = h1;
      float2 tv = make_float2(fmaxf(h0,0.f), fmaxf(h1,0.f));
      *(float2*)&tilde[((s*TT + t)*BB + (b0+r))*HH + k] = tv;
      if (t+1 < TT){
        const float* xrow = feat + ((s*TT + (t+1))*BB + (b0+r))*II;
        float2 xv = *(const float2*)(xrow + k);
        z[r][k] = xv.x; z[r][k+1] = xv.y;
      }
    }
    __syncthreads();
  }
}

// ---------------- phase C: projections (unchanged) ----------------
__global__ __launch_bounds__(256) void proj_ic(const float* __restrict__ tilde,
                                               const float* __restrict__ Wi, const float* __restrict__ bi,
                                               const float* __restrict__ Wc, const float* __restrict__ bc,
                                               float* __restrict__ xi, float* __restrict__ xc){
  const int k = blockIdx.y;
  const int isc = blockIdx.z;
  const float* W = (isc ? Wc : Wi) + k*HH*HH;
  const float* bias = (isc ? bc : bi) + k*HH;
  float* out = isc ? xc : xi;
  const int m0 = blockIdx.x * 128;
  const int tid = threadIdx.x;
  __shared__ float Wl[HH*HH];
  __shared__ float Al[32*HH];
  for (int u = 0; u < 64; ++u) Wl[u*256 + tid] = W[u*256 + tid];
  const int tx = tid & 31, ty = tid >> 5;
  const int d0 = tx*4;
  float4 bv = *(const float4*)&bias[d0];
  __syncthreads();
  for (int ch = 0; ch < 4; ++ch){
    const float* Arow = tilde + (size_t)(k*TT*BB + m0 + ch*32)*HH;
    #pragma unroll
    for (int u = 0; u < 4; ++u)
      *(float4*)&Al[u*1024 + tid*4] = *(const float4*)&Arow[u*1024 + tid*4];
    __syncthreads();
    float4 a0 = bv, a1 = bv, a2 = bv, a3 = bv;
    for (int h = 0; h < HH; ++h){
      float4 w4 = *(const float4*)&Wl[h*HH + d0];
      float A0 = Al[(ty   )*HH + h], A1 = Al[(ty+ 8)*HH + h];
      float A2 = Al[(ty+16)*HH + h], A3 = Al[(ty+24)*HH + h];
      a0.x = fmaf(A0,w4.x,a0.x); a0.y = fmaf(A0,w4.y,a0.y); a0.z = fmaf(A0,w4.z,a0.z); a0.w = fmaf(A0,w4.w,a0.w);
      a1.x = fmaf(A1,w4.x,a1.x); a1.y = fmaf(A1,w4.y,a1.y); a1.z = fmaf(A1,w4.z,a1.z); a1.w = fmaf(A1,w4.w,a1.w);
      a2.x = fmaf(A2,w4.x,a2.x); a2.y = fmaf(A2,w4.y,a2.y); a2.z = fmaf(A2,w4.z,a2.z); a2.w = fmaf(A2,w4.w,a2.w);
      a3.x = fmaf(A3,w4.x,a3.x); a3.y = fmaf(A3,w4.y,a3.y); a3.z = fmaf(A3,w4.z,a3.z); a3.w = fmaf(A3,w4.w,a3.w);
    }
    float4 accs[4] = {a0,a1,a2,a3};
    #pragma unroll
    for (int i = 0; i < 4; ++i){
      int m = m0 + ch*32 + ty + 8*i;
      int t = m >> 7, b = m & 127;
      *(float4*)&out[((t*SS + k)*BB + b)*HH + d0] = accs[i];
    }
    __syncthreads();
  }
}

__global__ __launch_bounds__(256) void proj_fo(const float* __restrict__ tilde,
                                               const float* __restrict__ Wf, const float* __restrict__ bf,
                                               const float* __restrict__ Wo, const float* __restrict__ bo,
                                               float* __restrict__ xf, float* __restrict__ xo){
  const int iso = blockIdx.y;
  const float* W = iso ? Wo : Wf;
  const float* bias = iso ? bo : bf;
  float* out = iso ? xo : xf;
  const int m0 = blockIdx.x * 128;
  const int tid = threadIdx.x;
  __shared__ float Wl[HH*HH];
  __shared__ float Al[32*HH];
  for (int u = 0; u < 64; ++u) Wl[u*256 + tid] = W[u*256 + tid];
  const int tx = tid & 31, ty = tid >> 5;
  const int d0 = tx*4;
  float4 bv = *(const float4*)&bias[d0];
  __syncthreads();
  for (int ch = 0; ch < 4; ++ch){
    const float* Arow = tilde + (size_t)(m0 + ch*32)*HH;
    #pragma unroll
    for (int u = 0; u < 4; ++u)
      *(float4*)&Al[u*1024 + tid*4] = *(const float4*)&Arow[u*1024 + tid*4];
    __syncthreads();
    float4 a0 = bv, a1 = bv, a2 = bv, a3 = bv;
    for (int h = 0; h < HH; ++h){
      float4 w4 = *(const float4*)&Wl[h*HH + d0];
      float A0 = Al[(ty   )*HH + h], A1 = Al[(ty+ 8)*HH + h];
      float A2 = Al[(ty+16)*HH + h], A3 = Al[(ty+24)*HH + h];
      a0.x = fmaf(A0,w4.x,a0.x); a0.y = fmaf(A0,w4.y,a0.y); a0.z = fmaf(A0,w4.z,a0.z); a0.w = fmaf(A0,w4.w,a0.w);
      a1.x = fmaf(A1,w4.x,a1.x); a1.y = fmaf(A1,w4.y,a1.y); a1.z = fmaf(A1,w4.z,a1.z); a1.w = fmaf(A1,w4.w,a1.w);
      a2.x = fmaf(A2,w4.x,a2.x); a2.y = fmaf(A2,w4.y,a2.y); a2.z = fmaf(A2,w4.z,a2.z); a2.w = fmaf(A2,w4.w,a2.w);
      a3.x = fmaf(A3,w4.x,a3.x); a3.y = fmaf(A3,w4.y,a3.y); a3.z = fmaf(A3,w4.z,a3.z); a3.w = fmaf(A3,w4.w,a3.w);
    }
    float4 accs[4] = {a0,a1,a2,a3};
    #pragma unroll
    for (int i = 0; i < 4; ++i){
      int m = m0 + ch*32 + ty + 8*i;
      *(float4*)&out[(size_t)m*HH + d0] = accs[i];
    }
    __syncthreads();
  }
}

// ---------------- phase D: cooperative weight-stationary MI-LSTM scan ----------------
__device__ __forceinline__ void gbar(int* flags, int bk, int p){
  asm volatile("s_waitcnt vmcnt(0)" ::: "memory");
  __syncthreads();
  if (threadIdx.x == 0) asti(&flags[bk], p);
  if (threadIdx.x < NBLK){
    while (aldi(&flags[threadIdx.x]) < p) __builtin_amdgcn_s_sleep(2);
  }
  __syncthreads();
}

__global__ void zero_cnt(int* cnt){ if (threadIdx.x < 128) cnt[threadIdx.x] = 0; }

// 92 blocks x 512 threads. Block bk owns 32 Ubig columns (16KB LDS, persistent).
// GEMM: h staged TRANSPOSED hLT[d][b-swz]; 256 threads, tile 4 rows x 8 cols x 64-d-half:
//   per d: 1 b128 A (4 batch rows) + 2 b128 W (8 cols), 32 FMA -> 1.5B/FMA LDS.
// Partial sums -> panT[col][row] (transposed, 4-way floor) -> 512-thread epilogue:
//   reduce halves + x add + activation + full-line sc1 act stores.
__global__ __launch_bounds__(512) void mi_coop(
    const float* __restrict__ ubig,
    const float* __restrict__ xi, const float* __restrict__ xc,
    const float* __restrict__ xf, const float* __restrict__ xo,
    const float* __restrict__ headW, const float* __restrict__ headb,
    float* hR, float* cR,
    float* act, int* flags, float* __restrict__ out)
{
  const int bk = blockIdx.x;
  const int tid = threadIdx.x;
  __shared__ float Wl[128*32];                  // 16KB weights [d][col], persistent
  __shared__ __align__(16) float hLT[128*128];  // 64KB transposed state [d][b-swz]
  __shared__ __align__(16) float panT0[32*132]; // 16.9KB partials (d-half 0), [col][row]
  __shared__ __align__(16) float panT1[32*132]; // 16.9KB partials (d-half 1)
  __shared__ float lL[20*128];
  __shared__ float part[8][8];
  __shared__ float uL[2][10];
  const int colw = tid & 31, rg5 = tid >> 5;
  const int gcol = bk*32 + colw;
  for (int h = rg5; h < 128; h += 16) Wl[h*32 + colw] = ubig[(size_t)h*NCOL + gcol];

  int btype;
  if (bk < 40) btype = 0; else if (bk < 80) btype = 1;
  else if (bk < 84) btype = 2; else if (bk < 88) btype = 3; else btype = 4;

  // GEMM tile mapping (tid<256): rows r0..r0+3, cols c0..c0+7, d-half gdh
  const int rg = tid & 31, cg = (tid >> 5) & 3, gdh = (tid >> 7) & 1;
  const int r0 = rg*4, c0g = cg*8;
  const int rhi = r0 & 96, rlo = r0 & 31;

  // epilogue mapping (all 512): row erow, cols ec0..ec0+7
  const int erow = tid >> 2, ec0 = (tid & 3) * 8;
  const float* xrd = nullptr; size_t xrd_step = 0;
  if (btype != 4){
    if (btype == 0){ int k = bk >> 2; int dloc = (bk & 3)*32 + ec0;
      xrd = xi + ((size_t)k*BB + erow)*HH + dloc; xrd_step = (size_t)SS*BB*HH; }
    else if (btype == 1){ int k = (bk-40) >> 2; int dloc = ((bk-40) & 3)*32 + ec0;
      xrd = xc + ((size_t)k*BB + erow)*HH + dloc; xrd_step = (size_t)SS*BB*HH; }
    else if (btype == 2){ int dloc = (bk-80)*32 + ec0;
      xrd = xf + (size_t)erow*HH + dloc; xrd_step = (size_t)BB*HH; }
    else { int dloc = (bk-84)*32 + ec0;
      xrd = xo + (size_t)erow*HH + dloc; xrd_step = (size_t)BB*HH; }
  }

  const int prow = tid >> 8, pd = tid & 127, phalf = (tid >> 7) & 1;
  const int pb = bk*2 + prow;
  const bool isP = (bk < 64);
  float c_reg = 0.f;
  float hw = headW[pd];
  float hb = headb[0];
  if (isP && phalf == 0){ ast(&hR[pb*HH + pd], 0.f); ast(&cR[pb*HH + pd], 0.f); }

  int ph = 1;
  gbar(flags, bk, ph++);

  for (int t = 0; t < TT; ++t){
    // ---------- x prefetch (epilogue pattern: 8 consecutive cols of one row) ----------
    float4 xv0, xv1;
    if (btype != 4){
      const float* xp = xrd + (size_t)t*xrd_step;
      xv0 = *(const float4*)(xp); xv1 = *(const float4*)(xp + 4);
    } else { xv0 = xv1 = make_float4(0.f,0.f,0.f,0.f); }
    // ---------- stage state TRANSPOSED (dwordx4 sc1 loads, scalar swizzled LDS writes) ----------
    // hLT[d][col] where col = (b&96)|((b&31)^(((d>>2)&7)<<2))
    const float* src = (btype == 4) ? cR : hR;
    f32x4v sv[8];
    #pragma unroll
    for (int u = 0; u < 8; ++u) sv[u] = ald4(&src[(u*512 + tid)*4]);
    asm volatile("s_waitcnt vmcnt(0)" ::: "memory");
    #pragma unroll
    for (int u = 0; u < 8; ++u){
      int lin = u*512 + tid;       // float4 index: b = lin>>5, d0 = (lin&31)*4
      int b = lin >> 5;
      int d0s = (lin & 31) * 4;
      int key = ((lin & 31) & 7) << 2;          // = ((d>>2)&7)<<2 for d in d0s..d0s+3
      int colb = (b & 96) | ((b & 31) ^ key);
      float vals[4] = {sv[u].x, sv[u].y, sv[u].z, sv[u].w};
      #pragma unroll
      for (int q = 0; q < 4; ++q)
        hLT[(d0s + q)*128 + colb] = vals[q];
    }
    __syncthreads();
    // ---------- G: 4x8 register-tiled GEMM over d-half ----------
    if (tid < 256){
      float acc[4][8];
      #pragma unroll
      for (int i = 0; i < 4; ++i)
        #pragma unroll
        for (int j = 0; j < 8; ++j) acc[i][j] = 0.f;
      const int dbase = gdh * 64;
      #pragma unroll 4
      for (int dd = 0; dd < 64; ++dd){
        int d = dbase + dd;
        int key = ((d >> 2) & 7) << 2;
        float4 av = *(const float4*)&hLT[d*128 + (rhi | (rlo ^ key))];
        float4 w0 = *(const float4*)&Wl[d*32 + c0g];
        float4 w1 = *(const float4*)&Wl[d*32 + c0g + 4];
        float a[4] = {av.x, av.y, av.z, av.w};
        float w[8] = {w0.x, w0.y, w0.z, w0.w, w1.x, w1.y, w1.z, w1.w};
        #pragma unroll
        for (int i = 0; i < 4; ++i)
          #pragma unroll
          for (int j = 0; j < 8; ++j)
            acc[i][j] = fmaf(a[i], w[j], acc[i][j]);
      }
      float* pt = gdh ? panT1 : panT0;
      #pragma unroll
      for (int j = 0; j < 8; ++j)
        *(float4*)&pt[(c0g + j)*132 + r0] = make_float4(acc[0][j], acc[1][j], acc[2][j], acc[3][j]);
    }
    __syncthreads();
    // ---------- epilogue (512 thr): reduce halves + x + activation + act store ----------
    {
      float xvals[8] = {xv0.x, xv0.y, xv0.z, xv0.w, xv1.x, xv1.y, xv1.z, xv1.w};
      float vout[8];
      #pragma unroll
      for (int u = 0; u < 8; ++u){
        float pv = panT0[(ec0 + u)*132 + erow] + panT1[(ec0 + u)*132 + erow] + xvals[u];
        float v;
        if (btype == 1) v = tanhf(pv);
        else if (btype == 4) v = pv;
        else v = sigf(pv);
        vout[u] = v;
      }
      float* ap = &act[(size_t)erow*NCOL + (size_t)bk*32 + ec0];
      ast4(ap,     vout[0], vout[1], vout[2], vout[3]);
      ast4(ap + 4, vout[4], vout[5], vout[6], vout[7]);
    }
    gbar(flags, bk, ph++);
    // ---------- P: attention + cell update (blocks 0..63, 2 rows each) ----------
    const float* arow = act + (size_t)(isP ? pb : 0)*NCOL;
    if (isP){
      float cw = ald(&arow[2816 + pd]);
      float s5[5];
      #pragma unroll
      for (int j = 0; j < 5; ++j){
        int k = phalf + 2*j;
        float li = ald(&arow[k*128 + pd]) * ald(&arow[1280 + k*128 + pd]);
        lL[(prow*10 + k)*128 + pd] = li;
        s5[j] = li * cw;
      }
      #pragma unroll
      for (int j = 0; j < 5; ++j){
        float s = s5[j];
        s += __shfl_down(s, 32); s += __shfl_down(s, 16); s += __shfl_down(s, 8);
        s += __shfl_down(s, 4);  s += __shfl_down(s, 2);  s += __shfl_down(s, 1);
        if ((tid & 63) == 0) part[tid >> 6][j] = s;
      }
    }
    __syncthreads();
    if (isP && tid < 20){
      int row = tid / 10, k = tid - row*10;
      int wbase = row*4 + (k & 1)*2;
      uL[row][k] = tanhf(part[wbase][k >> 1] + part[wbase + 1][k >> 1]);
    }
    __syncthreads();
    if (isP){
      float m = uL[prow][0];
      #pragma unroll
      for (int k = 1; k < 10; ++k) m = fmaxf(m, uL[prow][k]);
      float e[10]; float es = 0.f;
      #pragma unroll
      for (int k = 0; k < 10; ++k){ e[k] = expf(uL[prow][k] - m); es += e[k]; }
      float inv = 1.f / es;
      float sh = 0.f;
      if (phalf == 0){
        float lm = 0.f;
        #pragma unroll
        for (int k = 0; k < 10; ++k) lm = fmaf(e[k]*inv, lL[(prow*10 + k)*128 + pd], lm);
        float f = ald(&arow[2560 + pd]);
        float o = ald(&arow[2688 + pd]);
        float cn = fmaf(f, c_reg, lm);
        float hn = o * tanhf(cn);
        c_reg = cn;
        ast(&hR[pb*HH + pd], hn);
        ast(&cR[pb*HH + pd], cn);
        sh = fmaxf(hn, 0.f) * hw;
      }
      float s = sh;
      s += __shfl_down(s, 32); s += __shfl_down(s, 16); s += __shfl_down(s, 8);
      s += __shfl_down(s, 4);  s += __shfl_down(s, 2);  s += __shfl_down(s, 1);
      if ((tid & 63) == 0) part[tid >> 6][6] = s;
    }
    __syncthreads();
    if (isP && tid < 2){
      float s = part[tid*4][6] + part[tid*4 + 1][6];
      out[t*BB + bk*2 + tid] = fmaxf(s + hb, 0.f);
    }
    gbar(flags, bk, ph++);
  }
}

extern "C" void kernel_launch(void* const* d_in, const int* in_sizes, int n_in,
                              void* d_out, int out_size, void* d_ws, size_t ws_size,
                              hipStream_t stream) {
  const float* feat  = (const float*)d_in[0];
  const float* Wih   = (const float*)d_in[1];
  const float* Whh   = (const float*)d_in[2];
  const float* bih   = (const float*)d_in[3];
  const float* bhh   = (const float*)d_in[4];
  const float* miWi  = (const float*)d_in[5];
  const float* miUi  = (const float*)d_in[6];
  const float* mibi  = (const float*)d_in[7];
  const float* miWc  = (const float*)d_in[8];
  const float* miUc  = (const float*)d_in[9];
  const float* mibc  = (const float*)d_in[10];
  const float* miWf  = (const float*)d_in[11];
  const float* miUf  = (const float*)d_in[12];
  const float* mibf  = (const float*)d_in[13];
  const float* miWo  = (const float*)d_in[14];
  const float* miUo  = (const float*)d_in[15];
  const float* mibo  = (const float*)d_in[16];
  const float* miWa  = (const float*)d_in[17];
  const float* headW = (const float*)d_in[18];
  const float* headb = (const float*)d_in[19];
  float* out = (float*)d_out;

  float* ws    = (float*)d_ws;
  float* w2t   = ws + OFF_W2T;
  float* bias2 = ws + OFF_BIAS2;
  float* ubig  = ws + OFF_UBIG;
  float* tilde = ws + OFF_TILDE;
  float* xi    = ws + OFF_XI;
  float* xc    = ws + OFF_XC;
  float* xf    = ws + OFF_XF;
  float* xo    = ws + OFF_XO;
  float* hR    = ws + OFF_HT;
  float* cR    = ws + OFF_CT;
  float* act   = ws + OFF_ACT;
  int*   flags = (int*)(ws + OFF_CNT);

  prep_w2t<<<dim3(SZ_W2T/256), dim3(256), 0, stream>>>(Wih, Whh, bih, bhh, w2t, bias2);
  prep_ubig<<<dim3((SZ_UBIG+255)/256), dim3(256), 0, stream>>>(miUi, miUc, miUf, miUo, miWa, ubig);
  zero_cnt<<<dim3(1), dim3(128), 0, stream>>>(flags);
  lstm_scan<<<dim3(160), dim3(512), 0, stream>>>(feat, w2t, bias2, tilde);
  proj_ic<<<dim3(256, SS, 2), dim3(256), 0, stream>>>(tilde, miWi, mibi, miWc, mibc, xi, xc);
  proj_fo<<<dim3(256, 2), dim3(256), 0, stream>>>(tilde, miWf, mibf, miWo, mibo, xf, xo);

  void* kargs[] = { (void*)&ubig, (void*)&xi, (void*)&xc, (void*)&xf, (void*)&xo,
                    (void*)&headW, (void*)&headb, (void*)&hR, (void*)&cR,
                    (void*)&act, (void*)&flags, (void*)&out };
  hipLaunchCooperativeKernel((const void*)mi_coop, dim3(NBLK), dim3(512), kargs, 0, stream);
}

// Round 11
// 7771.411 us; speedup vs baseline: 1.2372x; 1.2372x over previous
//
#include <hip/hip_runtime.h>
#include <math.h>

// Model: 10 parallel LSTMs -> MI-LSTM w/ stream attention -> linear head.
// All f32 (no fp32-input MFMA on CDNA4; accuracy threshold requires f32).
//
#define SS 10
#define TT 256
#define BB 128
#define HH 128
#define II 128
#define G4 512     // 4H
#define ZK 256     // I + H (fused [x|h] contraction)
#define NCOL 2944  // phase-D fused weight columns: Ui(1280)|Uc(1280)|Uf(128)|Uo(128)|Wa(128)
#define NBLK 92    // cooperative blocks: 92 x 32 cols = 2944

#define SZ_W2T   (SS*ZK*G4)        // 1,310,720
#define SZ_BIAS2 (SS*G4)           // 5,120
#define SZ_UBIG  (HH*NCOL)         // 376,832
#define SZ_TILDE (SS*TT*BB*HH)     // 41,943,040
#define SZ_X     (TT*SS*BB*HH)     // 41,943,040
#define SZ_XFO   (TT*BB*HH)        // 4,194,304

#define OFF_W2T   0
#define OFF_BIAS2 (OFF_W2T + SZ_W2T)
#define OFF_UBIG  (OFF_BIAS2 + SZ_BIAS2)
#define OFF_TILDE (OFF_UBIG + SZ_UBIG)
#define OFF_XI    (OFF_TILDE + SZ_TILDE)
#define OFF_XC    (OFF_XI + SZ_X)
#define OFF_XF    (OFF_XC + SZ_X)
#define OFF_XO    (OFF_XF + SZ_XFO)
#define OFF_HT    (OFF_XO + SZ_XFO)
#define OFF_CT    (OFF_HT + BB*HH)
#define OFF_ACT   (OFF_CT + BB*HH)
#define OFF_CNT   (OFF_ACT + BB*NCOL)

__device__ __forceinline__ float sigf(float x){ return 1.0f/(1.0f+expf(-x)); }

// per-access coherent ops (sc0/sc1 path; no cache-wide wb/inv)
__device__ __forceinline__ float ald(const float* p){
  return __hip_atomic_load(p, __ATOMIC_RELAXED, __HIP_MEMORY_SCOPE_AGENT);
}
__device__ __forceinline__ void ast(float* p, float v){
  __hip_atomic_store(p, v, __ATOMIC_RELAXED, __HIP_MEMORY_SCOPE_AGENT);
}
__device__ __forceinline__ int aldi(const int* p){
  return __hip_atomic_load(p, __ATOMIC_RELAXED, __HIP_MEMORY_SCOPE_AGENT);
}
__device__ __forceinline__ void asti(int* p, int v){
  __hip_atomic_store(p, v, __ATOMIC_RELAXED, __HIP_MEMORY_SCOPE_AGENT);
}
// 16B coherent ops. ext_vector_type binds to a VGPR quad (HIP float4 is a struct, cannot).
typedef float f32x4v __attribute__((ext_vector_type(4)));
__device__ __forceinline__ void ast4(float* p, float a, float b, float c, float d){
  f32x4v w; w.x = a; w.y = b; w.z = c; w.w = d;
  asm volatile("global_store_dwordx4 %0, %1, off sc0 sc1" :: "v"(p), "v"(w) : "memory");
}
__device__ __forceinline__ f32x4v ald4(const float* p){
  f32x4v r;
  asm volatile("global_load_dwordx4 %0, %1, off sc0 sc1" : "=v"(r) : "v"(p) : "memory");
  return r;
}

// ---------------- prep: fused transposed LSTM weights (b128-friendly) ----------------
__global__ __launch_bounds__(256) void prep_w2t(const float* __restrict__ Wih, const float* __restrict__ Whh,
                                                const float* __restrict__ bih, const float* __restrict__ bhh,
                                                float* __restrict__ w2t, float* __restrict__ bias2){
  int idx = blockIdx.x*256 + threadIdx.x;
  if (idx < SZ_W2T){
    int q = idx & 3; int j = (idx >> 2) & 511; int kk4 = (idx >> 11) & 63; int s = idx >> 17;
    int kk = kk4*4 + q;
    float v = (kk < II) ? Wih[(s*G4 + j)*II + kk] : Whh[(s*G4 + j)*HH + (kk - II)];
    w2t[idx] = v;
  }
  if (idx < SZ_BIAS2) bias2[idx] = bih[idx] + bhh[idx];
}

__global__ __launch_bounds__(256) void prep_ubig(const float* __restrict__ Ui, const float* __restrict__ Uc,
                                                 const float* __restrict__ Uf, const float* __restrict__ Uo,
                                                 const float* __restrict__ Wa, float* __restrict__ ubig){
  int idx = blockIdx.x*256 + threadIdx.x;
  if (idx >= SZ_UBIG) return;
  int col = idx % NCOL; int h = idx / NCOL;
  float v;
  if (col < 1280){ int k = col >> 7, d = col & 127; v = Ui[(k*HH + h)*HH + d]; }
  else if (col < 2560){ int c2 = col - 1280; int k = c2 >> 7, d = c2 & 127; v = Uc[(k*HH + h)*HH + d]; }
  else if (col < 2688){ v = Uf[h*HH + (col - 2560)]; }
  else if (col < 2816){ v = Uo[h*HH + (col - 2688)]; }
  else               { v = Wa[h*HH + (col - 2816)]; }
  ubig[idx] = v;
}

// ---------------- phase B: fused 10x LSTM scan, split-K 1024 threads ----------------
// half 0 (tid<512): contract kk 0..127 (x-part, + bias); half 1: kk 128..255 (h-part).
// Partials combined in LDS. 32 independent weight loads/thread, 4 waves/SIMD.
__global__ __launch_bounds__(1024) void lstm_scan(const float* __restrict__ feat, const float* __restrict__ w2t,
                                                  const float* __restrict__ bias2, float* __restrict__ tilde){
  int p = blockIdx.x;                 // 0..159
  int g = (p & 7) * 20 + (p >> 3);    // XCD-contiguous logical id
  int s = g >> 4; int rb = g & 15; int b0 = rb * 8;
  const int tid = threadIdx.x;
  const int j = tid & 511;
  const int half = tid >> 9;
  const int ur = tid >> 7 >= 8 ? (tid - 1024) : (tid >> 7);  // placeholder (unused form)
  __shared__ float z[8][ZK];       // [row][x(128)|h(128)]  8KB
  __shared__ float glp[8][G4];     // half-1 partial sums   16KB
  __shared__ float gl[8][G4];      // activated gates       16KB
  const float* w2ts = w2t + (size_t)s*ZK*G4;
  // w4t [kk4][j][4]: base for this thread's half
  const float* wb = w2ts + ((size_t)(half*32)*G4 + j)*4;
  float bj = (half == 0) ? bias2[s*G4 + j] : 0.f;
  // update role: one (row, col) per thread
  const int r8 = tid >> 7;         // 0..7
  const int k8 = tid & 127;
  float c = 0.f;
  z[r8][128 + k8] = 0.f;
  z[r8][k8] = feat[((s*TT + 0)*BB + (b0 + r8))*II + k8];
  __syncthreads();
  for (int t = 0; t < TT; ++t){
    float acc[8];
    #pragma unroll
    for (int r=0;r<8;++r) acc[r] = bj;
    const float* wp = wb;
    const int kb0 = half*128;
    for (int kk4 = 0; kk4 < 32; ++kk4){
      float4 wv = *(const float4*)wp;
      wp += 4*G4;
      #pragma unroll
      for (int r=0;r<8;++r){
        float4 zv = *(const float4*)&z[r][kb0 + kk4*4];
        acc[r] = fmaf(zv.w, wv.w, fmaf(zv.z, wv.z, fmaf(zv.y, wv.y, fmaf(zv.x, wv.x, acc[r]))));
      }
    }
    if (half == 1){
      #pragma unroll
      for (int r=0;r<8;++r) glp[r][j] = acc[r];
    }
    __syncthreads();
    if (half == 0){
      int gtype = j >> 7;
      #pragma unroll
      for (int r=0;r<8;++r){
        float v = acc[r] + glp[r][j];
        v = (gtype == 2) ? tanhf(v) : sigf(v);
        gl[r][j] = v;
      }
    }
    __syncthreads();
    {
      float si = gl[r8][k8];
      float sf = gl[r8][128 + k8];
      float tg = gl[r8][256 + k8];
      float so = gl[r8][384 + k8];
      c = sf*c + si*tg;
      float h = so*tanhf(c);
      z[r8][128 + k8] = h;
      tilde[((s*TT + t)*BB + (b0 + r8))*HH + k8] = fmaxf(h, 0.f);
      if (t+1 < TT)
        z[r8][k8] = feat[((s*TT + (t+1))*BB + (b0 + r8))*II + k8];
    }
    __syncthreads();
  }
  (void)ur;
}

// ---------------- phase C: projections (unchanged) ----------------
__global__ __launch_bounds__(256) void proj_ic(const float* __restrict__ tilde,
                                               const float* __restrict__ Wi, const float* __restrict__ bi,
                                               const float* __restrict__ Wc, const float* __restrict__ bc,
                                               float* __restrict__ xi, float* __restrict__ xc){
  const int k = blockIdx.y;
  const int isc = blockIdx.z;
  const float* W = (isc ? Wc : Wi) + k*HH*HH;
  const float* bias = (isc ? bc : bi) + k*HH;
  float* out = isc ? xc : xi;
  const int m0 = blockIdx.x * 128;
  const int tid = threadIdx.x;
  __shared__ float Wl[HH*HH];
  __shared__ float Al[32*HH];
  for (int u = 0; u < 64; ++u) Wl[u*256 + tid] = W[u*256 + tid];
  const int tx = tid & 31, ty = tid >> 5;
  const int d0 = tx*4;
  float4 bv = *(const float4*)&bias[d0];
  __syncthreads();
  for (int ch = 0; ch < 4; ++ch){
    const float* Arow = tilde + (size_t)(k*TT*BB + m0 + ch*32)*HH;
    #pragma unroll
    for (int u = 0; u < 4; ++u)
      *(float4*)&Al[u*1024 + tid*4] = *(const float4*)&Arow[u*1024 + tid*4];
    __syncthreads();
    float4 a0 = bv, a1 = bv, a2 = bv, a3 = bv;
    for (int h = 0; h < HH; ++h){
      float4 w4 = *(const float4*)&Wl[h*HH + d0];
      float A0 = Al[(ty   )*HH + h], A1 = Al[(ty+ 8)*HH + h];
      float A2 = Al[(ty+16)*HH + h], A3 = Al[(ty+24)*HH + h];
      a0.x = fmaf(A0,w4.x,a0.x); a0.y = fmaf(A0,w4.y,a0.y); a0.z = fmaf(A0,w4.z,a0.z); a0.w = fmaf(A0,w4.w,a0.w);
      a1.x = fmaf(A1,w4.x,a1.x); a1.y = fmaf(A1,w4.y,a1.y); a1.z = fmaf(A1,w4.z,a1.z); a1.w = fmaf(A1,w4.w,a1.w);
      a2.x = fmaf(A2,w4.x,a2.x); a2.y = fmaf(A2,w4.y,a2.y); a2.z = fmaf(A2,w4.z,a2.z); a2.w = fmaf(A2,w4.w,a2.w);
      a3.x = fmaf(A3,w4.x,a3.x); a3.y = fmaf(A3,w4.y,a3.y); a3.z = fmaf(A3,w4.z,a3.z); a3.w = fmaf(A3,w4.w,a3.w);
    }
    float4 accs[4] = {a0,a1,a2,a3};
    #pragma unroll
    for (int i = 0; i < 4; ++i){
      int m = m0 + ch*32 + ty + 8*i;
      int t = m >> 7, b = m & 127;
      *(float4*)&out[((t*SS + k)*BB + b)*HH + d0] = accs[i];
    }
    __syncthreads();
  }
}

__global__ __launch_bounds__(256) void proj_fo(const float* __restrict__ tilde,
                                               const float* __restrict__ Wf, const float* __restrict__ bf,
                                               const float* __restrict__ Wo, const float* __restrict__ bo,
                                               float* __restrict__ xf, float* __restrict__ xo){
  const int iso = blockIdx.y;
  const float* W = iso ? Wo : Wf;
  const float* bias = iso ? bo : bf;
  float* out = iso ? xo : xf;
  const int m0 = blockIdx.x * 128;
  const int tid = threadIdx.x;
  __shared__ float Wl[HH*HH];
  __shared__ float Al[32*HH];
  for (int u = 0; u < 64; ++u) Wl[u*256 + tid] = W[u*256 + tid];
  const int tx = tid & 31, ty = tid >> 5;
  const int d0 = tx*4;
  float4 bv = *(const float4*)&bias[d0];
  __syncthreads();
  for (int ch = 0; ch < 4; ++ch){
    const float* Arow = tilde + (size_t)(m0 + ch*32)*HH;
    #pragma unroll
    for (int u = 0; u < 4; ++u)
      *(float4*)&Al[u*1024 + tid*4] = *(const float4*)&Arow[u*1024 + tid*4];
    __syncthreads();
    float4 a0 = bv, a1 = bv, a2 = bv, a3 = bv;
    for (int h = 0; h < HH; ++h){
      float4 w4 = *(const float4*)&Wl[h*HH + d0];
      float A0 = Al[(ty   )*HH + h], A1 = Al[(ty+ 8)*HH + h];
      float A2 = Al[(ty+16)*HH + h], A3 = Al[(ty+24)*HH + h];
      a0.x = fmaf(A0,w4.x,a0.x); a0.y = fmaf(A0,w4.y,a0.y); a0.z = fmaf(A0,w4.z,a0.z); a0.w = fmaf(A0,w4.w,a0.w);
      a1.x = fmaf(A1,w4.x,a1.x); a1.y = fmaf(A1,w4.y,a1.y); a1.z = fmaf(A1,w4.z,a1.z); a1.w = fmaf(A1,w4.w,a1.w);
      a2.x = fmaf(A2,w4.x,a2.x); a2.y = fmaf(A2,w4.y,a2.y); a2.z = fmaf(A2,w4.z,a2.z); a2.w = fmaf(A2,w4.w,a2.w);
      a3.x = fmaf(A3,w4.x,a3.x); a3.y = fmaf(A3,w4.y,a3.y); a3.z = fmaf(A3,w4.z,a3.z); a3.w = fmaf(A3,w4.w,a3.w);
    }
    float4 accs[4] = {a0,a1,a2,a3};
    #pragma unroll
    for (int i = 0; i < 4; ++i){
      int m = m0 + ch*32 + ty + 8*i;
      *(float4*)&out[(size_t)m*HH + d0] = accs[i];
    }
    __syncthreads();
  }
}

// ---------------- phase D: cooperative weight-stationary MI-LSTM scan ----------------
__device__ __forceinline__ void gbar(int* flags, int bk, int p){
  asm volatile("s_waitcnt vmcnt(0)" ::: "memory");
  __syncthreads();
  if (threadIdx.x == 0) asti(&flags[bk], p);
  if (threadIdx.x < NBLK){
    while (aldi(&flags[threadIdx.x]) < p) __builtin_amdgcn_s_sleep(2);
  }
  __syncthreads();
}

__global__ void zero_cnt(int* cnt){ if (threadIdx.x < 128) cnt[threadIdx.x] = 0; }

// 92 blocks x 512 threads. Block bk owns 32 Ubig columns (16KB LDS, persistent).
// GEMM: h staged TRANSPOSED hLT[d][b-swz]; 256 threads, tile 4 rows x 8 cols x 64-d-half:
//   per d: 1 b128 A (4 batch rows) + 2 b128 W (8 cols), 32 FMA -> 1.5B/FMA LDS.
// Partial sums -> panT[col][row] (transposed, 4-way floor) -> 512-thread epilogue:
//   reduce halves + x add + activation + full-line sc1 act stores.
__global__ __launch_bounds__(512) void mi_coop(
    const float* __restrict__ ubig,
    const float* __restrict__ xi, const float* __restrict__ xc,
    const float* __restrict__ xf, const float* __restrict__ xo,
    const float* __restrict__ headW, const float* __restrict__ headb,
    float* hR, float* cR,
    float* act, int* flags, float* __restrict__ out)
{
  const int bk = blockIdx.x;
  const int tid = threadIdx.x;
  __shared__ float Wl[128*32];                  // 16KB weights [d][col], persistent
  __shared__ __align__(16) float hLT[128*128];  // 64KB transposed state [d][b-swz]
  __shared__ __align__(16) float panT0[32*132]; // 16.9KB partials (d-half 0), [col][row]
  __shared__ __align__(16) float panT1[32*132]; // 16.9KB partials (d-half 1)
  __shared__ float lL[20*128];
  __shared__ float part[8][8];
  __shared__ float uL[2][10];
  const int colw = tid & 31, rg5 = tid >> 5;
  const int gcol = bk*32 + colw;
  for (int h = rg5; h < 128; h += 16) Wl[h*32 + colw] = ubig[(size_t)h*NCOL + gcol];

  int btype;
  if (bk < 40) btype = 0; else if (bk < 80) btype = 1;
  else if (bk < 84) btype = 2; else if (bk < 88) btype = 3; else btype = 4;

  // GEMM tile mapping (tid<256): rows r0..r0+3, cols c0..c0+7, d-half gdh
  const int rg = tid & 31, cg = (tid >> 5) & 3, gdh = (tid >> 7) & 1;
  const int r0 = rg*4, c0g = cg*8;
  const int rhi = r0 & 96, rlo = r0 & 31;

  // epilogue mapping (all 512): row erow, cols ec0..ec0+7
  const int erow = tid >> 2, ec0 = (tid & 3) * 8;
  const float* xrd = nullptr; size_t xrd_step = 0;
  if (btype != 4){
    if (btype == 0){ int k = bk >> 2; int dloc = (bk & 3)*32 + ec0;
      xrd = xi + ((size_t)k*BB + erow)*HH + dloc; xrd_step = (size_t)SS*BB*HH; }
    else if (btype == 1){ int k = (bk-40) >> 2; int dloc = ((bk-40) & 3)*32 + ec0;
      xrd = xc + ((size_t)k*BB + erow)*HH + dloc; xrd_step = (size_t)SS*BB*HH; }
    else if (btype == 2){ int dloc = (bk-80)*32 + ec0;
      xrd = xf + (size_t)erow*HH + dloc; xrd_step = (size_t)BB*HH; }
    else { int dloc = (bk-84)*32 + ec0;
      xrd = xo + (size_t)erow*HH + dloc; xrd_step = (size_t)BB*HH; }
  }

  const int prow = tid >> 8, pd = tid & 127, phalf = (tid >> 7) & 1;
  const int pb = bk*2 + prow;
  const bool isP = (bk < 64);
  float c_reg = 0.f;
  float hw = headW[pd];
  float hb = headb[0];
  if (isP && phalf == 0){ ast(&hR[pb*HH + pd], 0.f); ast(&cR[pb*HH + pd], 0.f); }

  int ph = 1;
  gbar(flags, bk, ph++);

  for (int t = 0; t < TT; ++t){
    // ---------- x prefetch (epilogue pattern: 8 consecutive cols of one row) ----------
    float4 xv0, xv1;
    if (btype != 4){
      const float* xp = xrd + (size_t)t*xrd_step;
      xv0 = *(const float4*)(xp); xv1 = *(const float4*)(xp + 4);
    } else { xv0 = xv1 = make_float4(0.f,0.f,0.f,0.f); }
    // ---------- stage state TRANSPOSED (dwordx4 sc1 loads, scalar swizzled LDS writes) ----------
    // hLT[d][col] where col = (b&96)|((b&31)^(((d>>2)&7)<<2))
    const float* src = (btype == 4) ? cR : hR;
    f32x4v sv[8];
    #pragma unroll
    for (int u = 0; u < 8; ++u) sv[u] = ald4(&src[(u*512 + tid)*4]);
    asm volatile("s_waitcnt vmcnt(0)" ::: "memory");
    #pragma unroll
    for (int u = 0; u < 8; ++u){
      int lin = u*512 + tid;       // float4 index: b = lin>>5, d0 = (lin&31)*4
      int b = lin >> 5;
      int d0s = (lin & 31) * 4;
      int key = ((lin & 31) & 7) << 2;          // = ((d>>2)&7)<<2 for d in d0s..d0s+3
      int colb = (b & 96) | ((b & 31) ^ key);
      float vals[4] = {sv[u].x, sv[u].y, sv[u].z, sv[u].w};
      #pragma unroll
      for (int q = 0; q < 4; ++q)
        hLT[(d0s + q)*128 + colb] = vals[q];
    }
    __syncthreads();
    // ---------- G: 4x8 register-tiled GEMM over d-half ----------
    if (tid < 256){
      float acc[4][8];
      #pragma unroll
      for (int i = 0; i < 4; ++i)
        #pragma unroll
        for (int j = 0; j < 8; ++j) acc[i][j] = 0.f;
      const int dbase = gdh * 64;
      #pragma unroll 4
      for (int dd = 0; dd < 64; ++dd){
        int d = dbase + dd;
        int key = ((d >> 2) & 7) << 2;
        float4 av = *(const float4*)&hLT[d*128 + (rhi | (rlo ^ key))];
        float4 w0 = *(const float4*)&Wl[d*32 + c0g];
        float4 w1 = *(const float4*)&Wl[d*32 + c0g + 4];
        float a[4] = {av.x, av.y, av.z, av.w};
        float w[8] = {w0.x, w0.y, w0.z, w0.w, w1.x, w1.y, w1.z, w1.w};
        #pragma unroll
        for (int i = 0; i < 4; ++i)
          #pragma unroll
          for (int j = 0; j < 8; ++j)
            acc[i][j] = fmaf(a[i], w[j], acc[i][j]);
      }
      float* pt = gdh ? panT1 : panT0;
      #pragma unroll
      for (int j = 0; j < 8; ++j)
        *(float4*)&pt[(c0g + j)*132 + r0] = make_float4(acc[0][j], acc[1][j], acc[2][j], acc[3][j]);
    }
    __syncthreads();
    // ---------- epilogue (512 thr): reduce halves + x + activation + act store ----------
    {
      float xvals[8] = {xv0.x, xv0.y, xv0.z, xv0.w, xv1.x, xv1.y, xv1.z, xv1.w};
      float vout[8];
      #pragma unroll
      for (int u = 0; u < 8; ++u){
        float pv = panT0[(ec0 + u)*132 + erow] + panT1[(ec0 + u)*132 + erow] + xvals[u];
        float v;
        if (btype == 1) v = tanhf(pv);
        else if (btype == 4) v = pv;
        else v = sigf(pv);
        vout[u] = v;
      }
      float* ap = &act[(size_t)erow*NCOL + (size_t)bk*32 + ec0];
      ast4(ap,     vout[0], vout[1], vout[2], vout[3]);
      ast4(ap + 4, vout[4], vout[5], vout[6], vout[7]);
    }
    gbar(flags, bk, ph++);
    // ---------- P: attention + cell update (blocks 0..63, 2 rows each) ----------
    const float* arow = act + (size_t)(isP ? pb : 0)*NCOL;
    if (isP){
      float cw = ald(&arow[2816 + pd]);
      float s5[5];
      #pragma unroll
      for (int j = 0; j < 5; ++j){
        int k = phalf + 2*j;
        float li = ald(&arow[k*128 + pd]) * ald(&arow[1280 + k*128 + pd]);
        lL[(prow*10 + k)*128 + pd] = li;
        s5[j] = li * cw;
      }
      #pragma unroll
      for (int j = 0; j < 5; ++j){
        float s = s5[j];
        s += __shfl_down(s, 32); s += __shfl_down(s, 16); s += __shfl_down(s, 8);
        s += __shfl_down(s, 4);  s += __shfl_down(s, 2);  s += __shfl_down(s, 1);
        if ((tid & 63) == 0) part[tid >> 6][j] = s;
      }
    }
    __syncthreads();
    if (isP && tid < 20){
      int row = tid / 10, k = tid - row*10;
      int wbase = row*4 + (k & 1)*2;
      uL[row][k] = tanhf(part[wbase][k >> 1] + part[wbase + 1][k >> 1]);
    }
    __syncthreads();
    if (isP){
      float m = uL[prow][0];
      #pragma unroll
      for (int k = 1; k < 10; ++k) m = fmaxf(m, uL[prow][k]);
      float e[10]; float es = 0.f;
      #pragma unroll
      for (int k = 0; k < 10; ++k){ e[k] = expf(uL[prow][k] - m); es += e[k]; }
      float inv = 1.f / es;
      float sh = 0.f;
      if (phalf == 0){
        float lm = 0.f;
        #pragma unroll
        for (int k = 0; k < 10; ++k) lm = fmaf(e[k]*inv, lL[(prow*10 + k)*128 + pd], lm);
        float f = ald(&arow[2560 + pd]);
        float o = ald(&arow[2688 + pd]);
        float cn = fmaf(f, c_reg, lm);
        float hn = o * tanhf(cn);
        c_reg = cn;
        ast(&hR[pb*HH + pd], hn);
        ast(&cR[pb*HH + pd], cn);
        sh = fmaxf(hn, 0.f) * hw;
      }
      float s = sh;
      s += __shfl_down(s, 32); s += __shfl_down(s, 16); s += __shfl_down(s, 8);
      s += __shfl_down(s, 4);  s += __shfl_down(s, 2);  s += __shfl_down(s, 1);
      if ((tid & 63) == 0) part[tid >> 6][6] = s;
    }
    __syncthreads();
    if (isP && tid < 2){
      float s = part[tid*4][6] + part[tid*4 + 1][6];
      out[t*BB + bk*2 + tid] = fmaxf(s + hb, 0.f);
    }
    gbar(flags, bk, ph++);
  }
}

extern "C" void kernel_launch(void* const* d_in, const int* in_sizes, int n_in,
                              void* d_out, int out_size, void* d_ws, size_t ws_size,
                              hipStream_t stream) {
  const float* feat  = (const float*)d_in[0];
  const float* Wih   = (const float*)d_in[1];
  const float* Whh   = (const float*)d_in[2];
  const float* bih   = (const float*)d_in[3];
  const float* bhh   = (const float*)d_in[4];
  const float* miWi  = (const float*)d_in[5];
  const float* miUi  = (const float*)d_in[6];
  const float* mibi  = (const float*)d_in[7];
  const float* miWc  = (const float*)d_in[8];
  const float* miUc  = (const float*)d_in[9];
  const float* mibc  = (const float*)d_in[10];
  const float* miWf  = (const float*)d_in[11];
  const float* miUf  = (const float*)d_in[12];
  const float* mibf  = (const float*)d_in[13];
  const float* miWo  = (const float*)d_in[14];
  const float* miUo  = (const float*)d_in[15];
  const float* mibo  = (const float*)d_in[16];
  const float* miWa  = (const float*)d_in[17];
  const float* headW = (const float*)d_in[18];
  const float* headb = (const float*)d_in[19];
  float* out = (float*)d_out;

  float* ws    = (float*)d_ws;
  float* w2t   = ws + OFF_W2T;
  float* bias2 = ws + OFF_BIAS2;
  float* ubig  = ws + OFF_UBIG;
  float* tilde = ws + OFF_TILDE;
  float* xi    = ws + OFF_XI;
  float* xc    = ws + OFF_XC;
  float* xf    = ws + OFF_XF;
  float* xo    = ws + OFF_XO;
  float* hR    = ws + OFF_HT;
  float* cR    = ws + OFF_CT;
  float* act   = ws + OFF_ACT;
  int*   flags = (int*)(ws + OFF_CNT);

  prep_w2t<<<dim3(SZ_W2T/256), dim3(256), 0, stream>>>(Wih, Whh, bih, bhh, w2t, bias2);
  prep_ubig<<<dim3((SZ_UBIG+255)/256), dim3(256), 0, stream>>>(miUi, miUc, miUf, miUo, miWa, ubig);
  zero_cnt<<<dim3(1), dim3(128), 0, stream>>>(flags);
  lstm_scan<<<dim3(160), dim3(1024), 0, stream>>>(feat, w2t, bias2, tilde);
  proj_ic<<<dim3(256, SS, 2), dim3(256), 0, stream>>>(tilde, miWi, mibi, miWc, mibc, xi, xc);
  proj_fo<<<dim3(256, 2), dim3(256), 0, stream>>>(tilde, miWf, mibf, miWo, mibo, xf, xo);

  void* kargs[] = { (void*)&ubig, (void*)&xi, (void*)&xc, (void*)&xf, (void*)&xo,
                    (void*)&headW, (void*)&headb, (void*)&hR, (void*)&cR,
                    (void*)&act, (void*)&flags, (void*)&out };
  hipLaunchCooperativeKernel((const void*)mi_coop, dim3(NBLK), dim3(512), kargs, 0, stream);
}

// Round 12
// 7572.342 us; speedup vs baseline: 1.2697x; 1.0263x over previous
//
#include <hip/hip_runtime.h>
#include <math.h>

// Model: 10 parallel LSTMs -> MI-LSTM w/ stream attention -> linear head.
// All f32 (no fp32-input MFMA on CDNA4; accuracy threshold requires f32).
//
#define SS 10
#define TT 256
#define BB 128
#define HH 128
#define II 128
#define G4 512     // 4H
#define ZK 256     // I + H (fused [x|h] contraction)
#define NCOL 2944  // phase-D fused weight columns: Ui(1280)|Uc(1280)|Uf(128)|Uo(128)|Wa(128)
#define NBLK 184   // cooperative blocks: 8 row-groups x 23 col-groups (16 rows x 128 cols each)

#define SZ_W2T   (SS*ZK*G4)        // 1,310,720
#define SZ_BIAS2 (SS*G4)           // 5,120
#define SZ_UBIG  (HH*NCOL)         // 376,832
#define SZ_TILDE (SS*TT*BB*HH)     // 41,943,040
#define SZ_X     (TT*SS*BB*HH)     // 41,943,040
#define SZ_XFO   (TT*BB*HH)        // 4,194,304

#define OFF_W2T   0
#define OFF_BIAS2 (OFF_W2T + SZ_W2T)
#define OFF_UBIG  (OFF_BIAS2 + SZ_BIAS2)
#define OFF_TILDE (OFF_UBIG + SZ_UBIG)
#define OFF_XI    (OFF_TILDE + SZ_TILDE)
#define OFF_XC    (OFF_XI + SZ_X)
#define OFF_XF    (OFF_XC + SZ_X)
#define OFF_XO    (OFF_XF + SZ_XFO)
#define OFF_HT    (OFF_XO + SZ_XFO)
#define OFF_CT    (OFF_HT + BB*HH)
#define OFF_ACT   (OFF_CT + BB*HH)
#define OFF_CNT   (OFF_ACT + BB*NCOL)

__device__ __forceinline__ float sigf(float x){ return 1.0f/(1.0f+expf(-x)); }

// per-access coherent ops (sc0/sc1 path; no cache-wide wb/inv)
__device__ __forceinline__ float ald(const float* p){
  return __hip_atomic_load(p, __ATOMIC_RELAXED, __HIP_MEMORY_SCOPE_AGENT);
}
__device__ __forceinline__ void ast(float* p, float v){
  __hip_atomic_store(p, v, __ATOMIC_RELAXED, __HIP_MEMORY_SCOPE_AGENT);
}
__device__ __forceinline__ int aldi(const int* p){
  return __hip_atomic_load(p, __ATOMIC_RELAXED, __HIP_MEMORY_SCOPE_AGENT);
}
__device__ __forceinline__ void asti(int* p, int v){
  __hip_atomic_store(p, v, __ATOMIC_RELAXED, __HIP_MEMORY_SCOPE_AGENT);
}
// 16B coherent ops. ext_vector_type binds to a VGPR quad (HIP float4 is a struct, cannot).
typedef float f32x4v __attribute__((ext_vector_type(4)));
__device__ __forceinline__ void ast4(float* p, float a, float b, float c, float d){
  f32x4v w; w.x = a; w.y = b; w.z = c; w.w = d;
  asm volatile("global_store_dwordx4 %0, %1, off sc0 sc1" :: "v"(p), "v"(w) : "memory");
}
__device__ __forceinline__ f32x4v ald4(const float* p){
  f32x4v r;
  asm volatile("global_load_dwordx4 %0, %1, off sc0 sc1" : "=v"(r) : "v"(p) : "memory");
  return r;
}

// ---------------- prep: fused transposed LSTM weights (b128-friendly) ----------------
__global__ __launch_bounds__(256) void prep_w2t(const float* __restrict__ Wih, const float* __restrict__ Whh,
                                                const float* __restrict__ bih, const float* __restrict__ bhh,
                                                float* __restrict__ w2t, float* __restrict__ bias2){
  int idx = blockIdx.x*256 + threadIdx.x;
  if (idx < SZ_W2T){
    int q = idx & 3; int j = (idx >> 2) & 511; int kk4 = (idx >> 11) & 63; int s = idx >> 17;
    int kk = kk4*4 + q;
    float v = (kk < II) ? Wih[(s*G4 + j)*II + kk] : Whh[(s*G4 + j)*HH + (kk - II)];
    w2t[idx] = v;
  }
  if (idx < SZ_BIAS2) bias2[idx] = bih[idx] + bhh[idx];
}

__global__ __launch_bounds__(256) void prep_ubig(const float* __restrict__ Ui, const float* __restrict__ Uc,
                                                 const float* __restrict__ Uf, const float* __restrict__ Uo,
                                                 const float* __restrict__ Wa, float* __restrict__ ubig){
  int idx = blockIdx.x*256 + threadIdx.x;
  if (idx >= SZ_UBIG) return;
  int col = idx % NCOL; int h = idx / NCOL;
  float v;
  if (col < 1280){ int k = col >> 7, d = col & 127; v = Ui[(k*HH + h)*HH + d]; }
  else if (col < 2560){ int c2 = col - 1280; int k = c2 >> 7, d = c2 & 127; v = Uc[(k*HH + h)*HH + d]; }
  else if (col < 2688){ v = Uf[h*HH + (col - 2560)]; }
  else if (col < 2816){ v = Uo[h*HH + (col - 2688)]; }
  else               { v = Wa[h*HH + (col - 2816)]; }
  ubig[idx] = v;
}

// ---------------- phase B: fused 10x LSTM scan, split-K 1024 threads (r11, kept) ----------------
__global__ __launch_bounds__(1024) void lstm_scan(const float* __restrict__ feat, const float* __restrict__ w2t,
                                                  const float* __restrict__ bias2, float* __restrict__ tilde){
  int p = blockIdx.x;                 // 0..159
  int g = (p & 7) * 20 + (p >> 3);
  int s = g >> 4; int rb = g & 15; int b0 = rb * 8;
  const int tid = threadIdx.x;
  const int j = tid & 511;
  const int half = tid >> 9;
  __shared__ float z[8][ZK];
  __shared__ float glp[8][G4];
  __shared__ float gl[8][G4];
  const float* w2ts = w2t + (size_t)s*ZK*G4;
  const float* wb = w2ts + ((size_t)(half*32)*G4 + j)*4;
  float bj = (half == 0) ? bias2[s*G4 + j] : 0.f;
  const int r8 = tid >> 7;
  const int k8 = tid & 127;
  float c = 0.f;
  z[r8][128 + k8] = 0.f;
  z[r8][k8] = feat[((s*TT + 0)*BB + (b0 + r8))*II + k8];
  __syncthreads();
  for (int t = 0; t < TT; ++t){
    float acc[8];
    #pragma unroll
    for (int r=0;r<8;++r) acc[r] = bj;
    const float* wp = wb;
    const int kb0 = half*128;
    for (int kk4 = 0; kk4 < 32; ++kk4){
      float4 wv = *(const float4*)wp;
      wp += 4*G4;
      #pragma unroll
      for (int r=0;r<8;++r){
        float4 zv = *(const float4*)&z[r][kb0 + kk4*4];
        acc[r] = fmaf(zv.w, wv.w, fmaf(zv.z, wv.z, fmaf(zv.y, wv.y, fmaf(zv.x, wv.x, acc[r]))));
      }
    }
    if (half == 1){
      #pragma unroll
      for (int r=0;r<8;++r) glp[r][j] = acc[r];
    }
    __syncthreads();
    if (half == 0){
      int gtype = j >> 7;
      #pragma unroll
      for (int r=0;r<8;++r){
        float v = acc[r] + glp[r][j];
        v = (gtype == 2) ? tanhf(v) : sigf(v);
        gl[r][j] = v;
      }
    }
    __syncthreads();
    {
      float si = gl[r8][k8];
      float sf = gl[r8][128 + k8];
      float tg = gl[r8][256 + k8];
      float so = gl[r8][384 + k8];
      c = sf*c + si*tg;
      float h = so*tanhf(c);
      z[r8][128 + k8] = h;
      tilde[((s*TT + t)*BB + (b0 + r8))*HH + k8] = fmaxf(h, 0.f);
      if (t+1 < TT)
        z[r8][k8] = feat[((s*TT + (t+1))*BB + (b0 + r8))*II + k8];
    }
    __syncthreads();
  }
}

// ---------------- phase C: projections (unchanged) ----------------
__global__ __launch_bounds__(256) void proj_ic(const float* __restrict__ tilde,
                                               const float* __restrict__ Wi, const float* __restrict__ bi,
                                               const float* __restrict__ Wc, const float* __restrict__ bc,
                                               float* __restrict__ xi, float* __restrict__ xc){
  const int k = blockIdx.y;
  const int isc = blockIdx.z;
  const float* W = (isc ? Wc : Wi) + k*HH*HH;
  const float* bias = (isc ? bc : bi) + k*HH;
  float* out = isc ? xc : xi;
  const int m0 = blockIdx.x * 128;
  const int tid = threadIdx.x;
  __shared__ float Wl[HH*HH];
  __shared__ float Al[32*HH];
  for (int u = 0; u < 64; ++u) Wl[u*256 + tid] = W[u*256 + tid];
  const int tx = tid & 31, ty = tid >> 5;
  const int d0 = tx*4;
  float4 bv = *(const float4*)&bias[d0];
  __syncthreads();
  for (int ch = 0; ch < 4; ++ch){
    const float* Arow = tilde + (size_t)(k*TT*BB + m0 + ch*32)*HH;
    #pragma unroll
    for (int u = 0; u < 4; ++u)
      *(float4*)&Al[u*1024 + tid*4] = *(const float4*)&Arow[u*1024 + tid*4];
    __syncthreads();
    float4 a0 = bv, a1 = bv, a2 = bv, a3 = bv;
    for (int h = 0; h < HH; ++h){
      float4 w4 = *(const float4*)&Wl[h*HH + d0];
      float A0 = Al[(ty   )*HH + h], A1 = Al[(ty+ 8)*HH + h];
      float A2 = Al[(ty+16)*HH + h], A3 = Al[(ty+24)*HH + h];
      a0.x = fmaf(A0,w4.x,a0.x); a0.y = fmaf(A0,w4.y,a0.y); a0.z = fmaf(A0,w4.z,a0.z); a0.w = fmaf(A0,w4.w,a0.w);
      a1.x = fmaf(A1,w4.x,a1.x); a1.y = fmaf(A1,w4.y,a1.y); a1.z = fmaf(A1,w4.z,a1.z); a1.w = fmaf(A1,w4.w,a1.w);
      a2.x = fmaf(A2,w4.x,a2.x); a2.y = fmaf(A2,w4.y,a2.y); a2.z = fmaf(A2,w4.z,a2.z); a2.w = fmaf(A2,w4.w,a2.w);
      a3.x = fmaf(A3,w4.x,a3.x); a3.y = fmaf(A3,w4.y,a3.y); a3.z = fmaf(A3,w4.z,a3.z); a3.w = fmaf(A3,w4.w,a3.w);
    }
    float4 accs[4] = {a0,a1,a2,a3};
    #pragma unroll
    for (int i = 0; i < 4; ++i){
      int m = m0 + ch*32 + ty + 8*i;
      int t = m >> 7, b = m & 127;
      *(float4*)&out[((t*SS + k)*BB + b)*HH + d0] = accs[i];
    }
    __syncthreads();
  }
}

__global__ __launch_bounds__(256) void proj_fo(const float* __restrict__ tilde,
                                               const float* __restrict__ Wf, const float* __restrict__ bf,
                                               const float* __restrict__ Wo, const float* __restrict__ bo,
                                               float* __restrict__ xf, float* __restrict__ xo){
  const int iso = blockIdx.y;
  const float* W = iso ? Wo : Wf;
  const float* bias = iso ? bo : bf;
  float* out = iso ? xo : xf;
  const int m0 = blockIdx.x * 128;
  const int tid = threadIdx.x;
  __shared__ float Wl[HH*HH];
  __shared__ float Al[32*HH];
  for (int u = 0; u < 64; ++u) Wl[u*256 + tid] = W[u*256 + tid];
  const int tx = tid & 31, ty = tid >> 5;
  const int d0 = tx*4;
  float4 bv = *(const float4*)&bias[d0];
  __syncthreads();
  for (int ch = 0; ch < 4; ++ch){
    const float* Arow = tilde + (size_t)(m0 + ch*32)*HH;
    #pragma unroll
    for (int u = 0; u < 4; ++u)
      *(float4*)&Al[u*1024 + tid*4] = *(const float4*)&Arow[u*1024 + tid*4];
    __syncthreads();
    float4 a0 = bv, a1 = bv, a2 = bv, a3 = bv;
    for (int h = 0; h < HH; ++h){
      float4 w4 = *(const float4*)&Wl[h*HH + d0];
      float A0 = Al[(ty   )*HH + h], A1 = Al[(ty+ 8)*HH + h];
      float A2 = Al[(ty+16)*HH + h], A3 = Al[(ty+24)*HH + h];
      a0.x = fmaf(A0,w4.x,a0.x); a0.y = fmaf(A0,w4.y,a0.y); a0.z = fmaf(A0,w4.z,a0.z); a0.w = fmaf(A0,w4.w,a0.w);
      a1.x = fmaf(A1,w4.x,a1.x); a1.y = fmaf(A1,w4.y,a1.y); a1.z = fmaf(A1,w4.z,a1.z); a1.w = fmaf(A1,w4.w,a1.w);
      a2.x = fmaf(A2,w4.x,a2.x); a2.y = fmaf(A2,w4.y,a2.y); a2.z = fmaf(A2,w4.z,a2.z); a2.w = fmaf(A2,w4.w,a2.w);
      a3.x = fmaf(A3,w4.x,a3.x); a3.y = fmaf(A3,w4.y,a3.y); a3.z = fmaf(A3,w4.z,a3.z); a3.w = fmaf(A3,w4.w,a3.w);
    }
    float4 accs[4] = {a0,a1,a2,a3};
    #pragma unroll
    for (int i = 0; i < 4; ++i){
      int m = m0 + ch*32 + ty + 8*i;
      *(float4*)&out[(size_t)m*HH + d0] = accs[i];
    }
    __syncthreads();
  }
}

// ---------------- phase D: cooperative 2D weight-stationary MI-LSTM scan ----------------
__device__ __forceinline__ void gbar(int* flags, int bk, int p){
  asm volatile("s_waitcnt vmcnt(0)" ::: "memory");
  __syncthreads();
  if (threadIdx.x == 0) asti(&flags[bk], p);
  if (threadIdx.x < NBLK){
    while (aldi(&flags[threadIdx.x]) < p) __builtin_amdgcn_s_sleep(2);
  }
  __syncthreads();
}

__global__ void zero_cnt(int* cnt){ if (threadIdx.x < 256) cnt[threadIdx.x] = 0; }

// 184 blocks x 512 threads. Block (rg = bk/23, cg = bk%23) owns output tile
// [16 rows x 128 cols]: Wl (64KB swizzled) LDS-resident; per step stage 16 h-rows
// (8KB) transposed+swizzled, 128-thread 8x8xd4 GEMM (<=2-way conflicts on hot
// reads), pan partial reduce, epilogue x-add + activation + full-line sc1 act
// stores -> flagbar -> P (128 blocks x 1 row) -> flagbar.
__global__ __launch_bounds__(512) void mi_coop(
    const float* __restrict__ ubig,
    const float* __restrict__ xi, const float* __restrict__ xc,
    const float* __restrict__ xf, const float* __restrict__ xo,
    const float* __restrict__ headW, const float* __restrict__ headb,
    float* hR, float* cR,
    float* act, int* flags, float* __restrict__ out)
{
  const int bk = blockIdx.x;
  const int tid = threadIdx.x;
  __shared__ float Wl[128*132];                 // 67.6KB weights [d][c^wkey], persistent
  __shared__ __align__(16) float hLT[128*20];   // 10KB transposed state [d][slot]
  __shared__ __align__(16) float pan[4*2564];   // 41KB partials [dsl][col*20 + rowslot]
  __shared__ float lL[10*128];
  __shared__ float part[8][8];
  __shared__ float uL[10];

  const int rg = bk / 23, cg = bk - rg*23;
  const int rb0 = rg*16;
  int btype; int xk = 0;
  if (cg < 10){ btype = 0; xk = cg; }
  else if (cg < 20){ btype = 1; xk = cg - 10; }
  else if (cg == 20) btype = 2;
  else if (cg == 21) btype = 3;
  else btype = 4;

  // weights: Wl[h*132 + (c ^ wkey(h))], wkey(h) = ((h>>5)&1)<<2
  for (int idx = tid; idx < 128*128; idx += 512){
    int h = idx >> 7, c = idx & 127;
    Wl[h*132 + (c ^ (((h>>5)&1)<<2))] = ubig[(size_t)h*NCOL + cg*128 + c];
  }

  // GEMM thread map (tid<128): dsl = tid&3 (32-d slice), ct = (tid>>2)&15, rt = tid>>6
  const int dsl = tid & 3, ctl = (tid >> 2) & 15, rt = tid >> 6;
  const int c0g = ctl*8;
  const int pkey = (ctl & 3) << 2;              // pan row-slot key (per col>>3)

  // epilogue map (all 512): row erow (0..15), cols ec0..ec0+3
  const int erow = tid >> 5, ec0 = (tid & 31) * 4;
  const float* xrd = nullptr; size_t xrd_step = 0;
  if (btype == 0){ xrd = xi + ((size_t)xk*BB + rb0 + erow)*HH + ec0; xrd_step = (size_t)SS*BB*HH; }
  else if (btype == 1){ xrd = xc + ((size_t)xk*BB + rb0 + erow)*HH + ec0; xrd_step = (size_t)SS*BB*HH; }
  else if (btype == 2){ xrd = xf + (size_t)(rb0 + erow)*HH + ec0; xrd_step = (size_t)BB*HH; }
  else if (btype == 3){ xrd = xo + (size_t)(rb0 + erow)*HH + ec0; xrd_step = (size_t)BB*HH; }

  // P map: 1 row per block (bk<128): quarter q over k = q+4j
  const bool isP = (bk < BB);
  const int q4 = tid >> 7, pd = tid & 127, wv = tid >> 6;
  const int pb = bk;
  float c_reg = 0.f;
  float hw = headW[pd];
  float hb = headb[0];
  if (isP && tid < 128){ ast(&hR[pb*HH + tid], 0.f); ast(&cR[pb*HH + tid], 0.f); }

  int ph = 1;
  gbar(flags, bk, ph++);

  for (int t = 0; t < TT; ++t){
    // ---------- x prefetch (epilogue pattern) ----------
    float4 xv = make_float4(0.f, 0.f, 0.f, 0.f);
    if (btype != 4) xv = *(const float4*)(xrd + (size_t)t*xrd_step);
    // ---------- stage 16 h-rows transposed (1 float4 sc1 load / thread) ----------
    // hLT[d*20 + ((b-rb0) ^ akey(d))], akey(d) = ((d>>4)&3)<<2
    const float* src = (btype == 4) ? cR : hR;
    {
      int bl = tid >> 5;                 // 0..15 local row
      int d4 = (tid & 31) * 4;
      f32x4v sv = ald4(&src[(size_t)(rb0 + bl)*HH + d4]);
      asm volatile("s_waitcnt vmcnt(0)" ::: "memory");
      int slot = bl ^ (((d4 >> 4) & 3) << 2);
      hLT[(d4+0)*20 + slot] = sv.x;
      hLT[(d4+1)*20 + slot] = sv.y;
      hLT[(d4+2)*20 + slot] = sv.z;
      hLT[(d4+3)*20 + slot] = sv.w;
    }
    __syncthreads();
    // ---------- G: 8r x 8c x 32d register-tiled GEMM (tid<128) ----------
    if (tid < 128){
      float acc[8][8];
      #pragma unroll
      for (int i = 0; i < 8; ++i)
        #pragma unroll
        for (int j = 0; j < 8; ++j) acc[i][j] = 0.f;
      const int wkey = (dsl & 1) << 2;   // = ((d>>5)&1)<<2 for this slice
      #pragma unroll 4
      for (int dd = 0; dd < 32; ++dd){
        int d = dsl*32 + dd;
        int akey = ((d >> 4) & 3) << 2;
        float4 a0 = *(const float4*)&hLT[d*20 + ((rt*8)     ^ akey)];
        float4 a1 = *(const float4*)&hLT[d*20 + ((rt*8 + 4) ^ akey)];
        float4 w0 = *(const float4*)&Wl[d*132 + ((c0g)      ^ wkey)];
        float4 w1 = *(const float4*)&Wl[d*132 + ((c0g + 4)  ^ wkey)];
        float a[8] = {a0.x, a0.y, a0.z, a0.w, a1.x, a1.y, a1.z, a1.w};
        float w[8] = {w0.x, w0.y, w0.z, w0.w, w1.x, w1.y, w1.z, w1.w};
        #pragma unroll
        for (int i = 0; i < 8; ++i)
          #pragma unroll
          for (int j = 0; j < 8; ++j)
            acc[i][j] = fmaf(a[i], w[j], acc[i][j]);
      }
      // pan[dsl][col*20 + (row ^ pkey)]
      float* pt = pan + dsl*2564;
      #pragma unroll
      for (int j = 0; j < 8; ++j){
        int cb = (c0g + j)*20;
        *(float4*)&pt[cb + ((rt*8)     ^ pkey)] = make_float4(acc[0][j], acc[1][j], acc[2][j], acc[3][j]);
        *(float4*)&pt[cb + ((rt*8 + 4) ^ pkey)] = make_float4(acc[4][j], acc[5][j], acc[6][j], acc[7][j]);
      }
    }
    __syncthreads();
    // ---------- epilogue (512 thr): reduce 4 partials + x + activation + act store ----------
    {
      float xvals[4] = {xv.x, xv.y, xv.z, xv.w};
      float vout[4];
      #pragma unroll
      for (int u = 0; u < 4; ++u){
        int col = ec0 + u;
        int slot = erow ^ (((col >> 3) & 3) << 2);
        int cb = col*20 + slot;
        float pv = pan[cb] + pan[2564 + cb] + pan[2*2564 + cb] + pan[3*2564 + cb] + xvals[u];
        float v;
        if (btype == 1) v = tanhf(pv);
        else if (btype == 4) v = pv;
        else v = sigf(pv);
        vout[u] = v;
      }
      float* ap = &act[(size_t)(rb0 + erow)*NCOL + (size_t)cg*128 + ec0];
      ast4(ap, vout[0], vout[1], vout[2], vout[3]);
    }
    gbar(flags, bk, ph++);
    // ---------- P: attention + cell update (blocks 0..127, 1 row each) ----------
    const float* arow = act + (size_t)(isP ? pb : 0)*NCOL;
    if (isP){
      float cw = ald(&arow[2816 + pd]);
      int nk = (q4 < 2) ? 3 : 2;
      #pragma unroll
      for (int j = 0; j < 3; ++j){
        float s = 0.f;
        if (j < nk){
          int k = q4 + 4*j;
          float li = ald(&arow[k*128 + pd]) * ald(&arow[1280 + k*128 + pd]);
          lL[k*128 + pd] = li;
          s = li * cw;
        }
        s += __shfl_down(s, 32); s += __shfl_down(s, 16); s += __shfl_down(s, 8);
        s += __shfl_down(s, 4);  s += __shfl_down(s, 2);  s += __shfl_down(s, 1);
        if ((tid & 63) == 0) part[wv][j] = s;
      }
    }
    __syncthreads();
    if (isP && tid < 10){
      int k = tid; int qq = k & 3; int j = k >> 2;
      uL[k] = tanhf(part[qq*2][j] + part[qq*2 + 1][j]);
    }
    __syncthreads();
    if (isP && tid < 128){
      float m = uL[0];
      #pragma unroll
      for (int k = 1; k < 10; ++k) m = fmaxf(m, uL[k]);
      float e[10]; float es = 0.f;
      #pragma unroll
      for (int k = 0; k < 10; ++k){ e[k] = expf(uL[k] - m); es += e[k]; }
      float inv = 1.f / es;
      float lm = 0.f;
      #pragma unroll
      for (int k = 0; k < 10; ++k) lm = fmaf(e[k]*inv, lL[k*128 + tid], lm);
      float f = ald(&arow[2560 + tid]);
      float o = ald(&arow[2688 + tid]);
      float cn = fmaf(f, c_reg, lm);
      float hn = o * tanhf(cn);
      c_reg = cn;
      ast(&hR[pb*HH + tid], hn);
      ast(&cR[pb*HH + tid], cn);
      float s = fmaxf(hn, 0.f) * hw;
      s += __shfl_down(s, 32); s += __shfl_down(s, 16); s += __shfl_down(s, 8);
      s += __shfl_down(s, 4);  s += __shfl_down(s, 2);  s += __shfl_down(s, 1);
      if ((tid & 63) == 0) part[wv][6] = s;
    }
    __syncthreads();
    if (isP && tid == 0)
      out[t*BB + pb] = fmaxf(part[0][6] + part[1][6] + hb, 0.f);
    gbar(flags, bk, ph++);
  }
}

extern "C" void kernel_launch(void* const* d_in, const int* in_sizes, int n_in,
                              void* d_out, int out_size, void* d_ws, size_t ws_size,
                              hipStream_t stream) {
  const float* feat  = (const float*)d_in[0];
  const float* Wih   = (const float*)d_in[1];
  const float* Whh   = (const float*)d_in[2];
  const float* bih   = (const float*)d_in[3];
  const float* bhh   = (const float*)d_in[4];
  const float* miWi  = (const float*)d_in[5];
  const float* miUi  = (const float*)d_in[6];
  const float* mibi  = (const float*)d_in[7];
  const float* miWc  = (const float*)d_in[8];
  const float* miUc  = (const float*)d_in[9];
  const float* mibc  = (const float*)d_in[10];
  const float* miWf  = (const float*)d_in[11];
  const float* miUf  = (const float*)d_in[12];
  const float* mibf  = (const float*)d_in[13];
  const float* miWo  = (const float*)d_in[14];
  const float* miUo  = (const float*)d_in[15];
  const float* mibo  = (const float*)d_in[16];
  const float* miWa  = (const float*)d_in[17];
  const float* headW = (const float*)d_in[18];
  const float* headb = (const float*)d_in[19];
  float* out = (float*)d_out;

  float* ws    = (float*)d_ws;
  float* w2t   = ws + OFF_W2T;
  float* bias2 = ws + OFF_BIAS2;
  float* ubig  = ws + OFF_UBIG;
  float* tilde = ws + OFF_TILDE;
  float* xi    = ws + OFF_XI;
  float* xc    = ws + OFF_XC;
  float* xf    = ws + OFF_XF;
  float* xo    = ws + OFF_XO;
  float* hR    = ws + OFF_HT;
  float* cR    = ws + OFF_CT;
  float* act   = ws + OFF_ACT;
  int*   flags = (int*)(ws + OFF_CNT);

  prep_w2t<<<dim3(SZ_W2T/256), dim3(256), 0, stream>>>(Wih, Whh, bih, bhh, w2t, bias2);
  prep_ubig<<<dim3((SZ_UBIG+255)/256), dim3(256), 0, stream>>>(miUi, miUc, miUf, miUo, miWa, ubig);
  zero_cnt<<<dim3(1), dim3(256), 0, stream>>>(flags);
  lstm_scan<<<dim3(160), dim3(1024), 0, stream>>>(feat, w2t, bias2, tilde);
  proj_ic<<<dim3(256, SS, 2), dim3(256), 0, stream>>>(tilde, miWi, mibi, miWc, mibc, xi, xc);
  proj_fo<<<dim3(256, 2), dim3(256), 0, stream>>>(tilde, miWf, mibf, miWo, mibo, xf, xo);

  void* kargs[] = { (void*)&ubig, (void*)&xi, (void*)&xc, (void*)&xf, (void*)&xo,
                    (void*)&headW, (void*)&headb, (void*)&hR, (void*)&cR,
                    (void*)&act, (void*)&flags, (void*)&out };
  hipLaunchCooperativeKernel((const void*)mi_coop, dim3(NBLK), dim3(512), kargs, 0, stream);
}

// Round 13
// 6784.291 us; speedup vs baseline: 1.4172x; 1.1162x over previous
//
#include <hip/hip_runtime.h>
#include <math.h>

// Model: 10 parallel LSTMs -> MI-LSTM w/ stream attention -> linear head.
// All f32 (no fp32-input MFMA on CDNA4; accuracy threshold requires f32).
//
#define SS 10
#define TT 256
#define BB 128
#define HH 128
#define II 128
#define G4 512     // 4H
#define ZK 256     // I + H (fused [x|h] contraction)
#define NCOL 2944  // phase-D fused weight columns: Ui(1280)|Uc(1280)|Uf(128)|Uo(128)|Wa(128)
#define NBLK 184   // cooperative blocks: 8 row-groups x 23 col-groups (16 rows x 128 cols each)

#define SZ_W2T   (SS*ZK*G4)        // 1,310,720
#define SZ_BIAS2 (SS*G4)           // 5,120
#define SZ_UBIG  (HH*NCOL)         // 376,832
#define SZ_TILDE (SS*TT*BB*HH)     // 41,943,040
#define SZ_X     (TT*SS*BB*HH)     // 41,943,040
#define SZ_XFO   (TT*BB*HH)        // 4,194,304

#define OFF_W2T   0
#define OFF_BIAS2 (OFF_W2T + SZ_W2T)
#define OFF_UBIG  (OFF_BIAS2 + SZ_BIAS2)
#define OFF_TILDE (OFF_UBIG + SZ_UBIG)
#define OFF_XI    (OFF_TILDE + SZ_TILDE)
#define OFF_XC    (OFF_XI + SZ_X)
#define OFF_XF    (OFF_XC + SZ_X)
#define OFF_XO    (OFF_XF + SZ_XFO)
#define OFF_HT    (OFF_XO + SZ_XFO)
#define OFF_CT    (OFF_HT + BB*HH)
#define OFF_ACT   (OFF_CT + BB*HH)
#define OFF_CNT   (OFF_ACT + BB*NCOL)

__device__ __forceinline__ float sigf(float x){ return 1.0f/(1.0f+expf(-x)); }

// per-access coherent ops (sc0/sc1 path; no cache-wide wb/inv)
__device__ __forceinline__ float ald(const float* p){
  return __hip_atomic_load(p, __ATOMIC_RELAXED, __HIP_MEMORY_SCOPE_AGENT);
}
__device__ __forceinline__ void ast(float* p, float v){
  __hip_atomic_store(p, v, __ATOMIC_RELAXED, __HIP_MEMORY_SCOPE_AGENT);
}
__device__ __forceinline__ int aldi(const int* p){
  return __hip_atomic_load(p, __ATOMIC_RELAXED, __HIP_MEMORY_SCOPE_AGENT);
}
__device__ __forceinline__ void asti(int* p, int v){
  __hip_atomic_store(p, v, __ATOMIC_RELAXED, __HIP_MEMORY_SCOPE_AGENT);
}
// 16B coherent ops. ext_vector_type binds to a VGPR quad (HIP float4 is a struct, cannot).
typedef float f32x4v __attribute__((ext_vector_type(4)));
__device__ __forceinline__ void ast4(float* p, float a, float b, float c, float d){
  f32x4v w; w.x = a; w.y = b; w.z = c; w.w = d;
  asm volatile("global_store_dwordx4 %0, %1, off sc0 sc1" :: "v"(p), "v"(w) : "memory");
}
__device__ __forceinline__ f32x4v ald4(const float* p){
  f32x4v r;
  asm volatile("global_load_dwordx4 %0, %1, off sc0 sc1" : "=v"(r) : "v"(p) : "memory");
  return r;
}

// ---------------- prep: fused transposed LSTM weights (b128-friendly) ----------------
__global__ __launch_bounds__(256) void prep_w2t(const float* __restrict__ Wih, const float* __restrict__ Whh,
                                                const float* __restrict__ bih, const float* __restrict__ bhh,
                                                float* __restrict__ w2t, float* __restrict__ bias2){
  int idx = blockIdx.x*256 + threadIdx.x;
  if (idx < SZ_W2T){
    int q = idx & 3; int j = (idx >> 2) & 511; int kk4 = (idx >> 11) & 63; int s = idx >> 17;
    int kk = kk4*4 + q;
    float v = (kk < II) ? Wih[(s*G4 + j)*II + kk] : Whh[(s*G4 + j)*HH + (kk - II)];
    w2t[idx] = v;
  }
  if (idx < SZ_BIAS2) bias2[idx] = bih[idx] + bhh[idx];
}

__global__ __launch_bounds__(256) void prep_ubig(const float* __restrict__ Ui, const float* __restrict__ Uc,
                                                 const float* __restrict__ Uf, const float* __restrict__ Uo,
                                                 const float* __restrict__ Wa, float* __restrict__ ubig){
  int idx = blockIdx.x*256 + threadIdx.x;
  if (idx >= SZ_UBIG) return;
  int col = idx % NCOL; int h = idx / NCOL;
  float v;
  if (col < 1280){ int k = col >> 7, d = col & 127; v = Ui[(k*HH + h)*HH + d]; }
  else if (col < 2560){ int c2 = col - 1280; int k = c2 >> 7, d = c2 & 127; v = Uc[(k*HH + h)*HH + d]; }
  else if (col < 2688){ v = Uf[h*HH + (col - 2560)]; }
  else if (col < 2816){ v = Uo[h*HH + (col - 2688)]; }
  else               { v = Wa[h*HH + (col - 2816)]; }
  ubig[idx] = v;
}

// init: flags + h/c state
__global__ __launch_bounds__(256) void init_state(int* flags, float* hR, float* cR){
  int idx = blockIdx.x*256 + threadIdx.x;
  if (idx < 384) flags[idx] = 0;
  if (idx < BB*HH){ hR[idx] = 0.f; cR[idx] = 0.f; }
}

// ---------------- phase B: fused 10x LSTM scan, split-K 1024 threads (r11, kept) ----------------
__global__ __launch_bounds__(1024) void lstm_scan(const float* __restrict__ feat, const float* __restrict__ w2t,
                                                  const float* __restrict__ bias2, float* __restrict__ tilde){
  int p = blockIdx.x;                 // 0..159
  int g = (p & 7) * 20 + (p >> 3);
  int s = g >> 4; int rb = g & 15; int b0 = rb * 8;
  const int tid = threadIdx.x;
  const int j = tid & 511;
  const int half = tid >> 9;
  __shared__ float z[8][ZK];
  __shared__ float glp[8][G4];
  __shared__ float gl[8][G4];
  const float* w2ts = w2t + (size_t)s*ZK*G4;
  const float* wb = w2ts + ((size_t)(half*32)*G4 + j)*4;
  float bj = (half == 0) ? bias2[s*G4 + j] : 0.f;
  const int r8 = tid >> 7;
  const int k8 = tid & 127;
  float c = 0.f;
  z[r8][128 + k8] = 0.f;
  z[r8][k8] = feat[((s*TT + 0)*BB + (b0 + r8))*II + k8];
  __syncthreads();
  for (int t = 0; t < TT; ++t){
    float acc[8];
    #pragma unroll
    for (int r=0;r<8;++r) acc[r] = bj;
    const float* wp = wb;
    const int kb0 = half*128;
    for (int kk4 = 0; kk4 < 32; ++kk4){
      float4 wv = *(const float4*)wp;
      wp += 4*G4;
      #pragma unroll
      for (int r=0;r<8;++r){
        float4 zv = *(const float4*)&z[r][kb0 + kk4*4];
        acc[r] = fmaf(zv.w, wv.w, fmaf(zv.z, wv.z, fmaf(zv.y, wv.y, fmaf(zv.x, wv.x, acc[r]))));
      }
    }
    if (half == 1){
      #pragma unroll
      for (int r=0;r<8;++r) glp[r][j] = acc[r];
    }
    __syncthreads();
    if (half == 0){
      int gtype = j >> 7;
      #pragma unroll
      for (int r=0;r<8;++r){
        float v = acc[r] + glp[r][j];
        v = (gtype == 2) ? tanhf(v) : sigf(v);
        gl[r][j] = v;
      }
    }
    __syncthreads();
    {
      float si = gl[r8][k8];
      float sf = gl[r8][128 + k8];
      float tg = gl[r8][256 + k8];
      float so = gl[r8][384 + k8];
      c = sf*c + si*tg;
      float h = so*tanhf(c);
      z[r8][128 + k8] = h;
      tilde[((s*TT + t)*BB + (b0 + r8))*HH + k8] = fmaxf(h, 0.f);
      if (t+1 < TT)
        z[r8][k8] = feat[((s*TT + (t+1))*BB + (b0 + r8))*II + k8];
    }
    __syncthreads();
  }
}

// ---------------- phase C: projections (unchanged) ----------------
__global__ __launch_bounds__(256) void proj_ic(const float* __restrict__ tilde,
                                               const float* __restrict__ Wi, const float* __restrict__ bi,
                                               const float* __restrict__ Wc, const float* __restrict__ bc,
                                               float* __restrict__ xi, float* __restrict__ xc){
  const int k = blockIdx.y;
  const int isc = blockIdx.z;
  const float* W = (isc ? Wc : Wi) + k*HH*HH;
  const float* bias = (isc ? bc : bi) + k*HH;
  float* out = isc ? xc : xi;
  const int m0 = blockIdx.x * 128;
  const int tid = threadIdx.x;
  __shared__ float Wl[HH*HH];
  __shared__ float Al[32*HH];
  for (int u = 0; u < 64; ++u) Wl[u*256 + tid] = W[u*256 + tid];
  const int tx = tid & 31, ty = tid >> 5;
  const int d0 = tx*4;
  float4 bv = *(const float4*)&bias[d0];
  __syncthreads();
  for (int ch = 0; ch < 4; ++ch){
    const float* Arow = tilde + (size_t)(k*TT*BB + m0 + ch*32)*HH;
    #pragma unroll
    for (int u = 0; u < 4; ++u)
      *(float4*)&Al[u*1024 + tid*4] = *(const float4*)&Arow[u*1024 + tid*4];
    __syncthreads();
    float4 a0 = bv, a1 = bv, a2 = bv, a3 = bv;
    for (int h = 0; h < HH; ++h){
      float4 w4 = *(const float4*)&Wl[h*HH + d0];
      float A0 = Al[(ty   )*HH + h], A1 = Al[(ty+ 8)*HH + h];
      float A2 = Al[(ty+16)*HH + h], A3 = Al[(ty+24)*HH + h];
      a0.x = fmaf(A0,w4.x,a0.x); a0.y = fmaf(A0,w4.y,a0.y); a0.z = fmaf(A0,w4.z,a0.z); a0.w = fmaf(A0,w4.w,a0.w);
      a1.x = fmaf(A1,w4.x,a1.x); a1.y = fmaf(A1,w4.y,a1.y); a1.z = fmaf(A1,w4.z,a1.z); a1.w = fmaf(A1,w4.w,a1.w);
      a2.x = fmaf(A2,w4.x,a2.x); a2.y = fmaf(A2,w4.y,a2.y); a2.z = fmaf(A2,w4.z,a2.z); a2.w = fmaf(A2,w4.w,a2.w);
      a3.x = fmaf(A3,w4.x,a3.x); a3.y = fmaf(A3,w4.y,a3.y); a3.z = fmaf(A3,w4.z,a3.z); a3.w = fmaf(A3,w4.w,a3.w);
    }
    float4 accs[4] = {a0,a1,a2,a3};
    #pragma unroll
    for (int i = 0; i < 4; ++i){
      int m = m0 + ch*32 + ty + 8*i;
      int t = m >> 7, b = m & 127;
      *(float4*)&out[((t*SS + k)*BB + b)*HH + d0] = accs[i];
    }
    __syncthreads();
  }
}

__global__ __launch_bounds__(256) void proj_fo(const float* __restrict__ tilde,
                                               const float* __restrict__ Wf, const float* __restrict__ bf,
                                               const float* __restrict__ Wo, const float* __restrict__ bo,
                                               float* __restrict__ xf, float* __restrict__ xo){
  const int iso = blockIdx.y;
  const float* W = iso ? Wo : Wf;
  const float* bias = iso ? bo : bf;
  float* out = iso ? xo : xf;
  const int m0 = blockIdx.x * 128;
  const int tid = threadIdx.x;
  __shared__ float Wl[HH*HH];
  __shared__ float Al[32*HH];
  for (int u = 0; u < 64; ++u) Wl[u*256 + tid] = W[u*256 + tid];
  const int tx = tid & 31, ty = tid >> 5;
  const int d0 = tx*4;
  float4 bv = *(const float4*)&bias[d0];
  __syncthreads();
  for (int ch = 0; ch < 4; ++ch){
    const float* Arow = tilde + (size_t)(m0 + ch*32)*HH;
    #pragma unroll
    for (int u = 0; u < 4; ++u)
      *(float4*)&Al[u*1024 + tid*4] = *(const float4*)&Arow[u*1024 + tid*4];
    __syncthreads();
    float4 a0 = bv, a1 = bv, a2 = bv, a3 = bv;
    for (int h = 0; h < HH; ++h){
      float4 w4 = *(const float4*)&Wl[h*HH + d0];
      float A0 = Al[(ty   )*HH + h], A1 = Al[(ty+ 8)*HH + h];
      float A2 = Al[(ty+16)*HH + h], A3 = Al[(ty+24)*HH + h];
      a0.x = fmaf(A0,w4.x,a0.x); a0.y = fmaf(A0,w4.y,a0.y); a0.z = fmaf(A0,w4.z,a0.z); a0.w = fmaf(A0,w4.w,a0.w);
      a1.x = fmaf(A1,w4.x,a1.x); a1.y = fmaf(A1,w4.y,a1.y); a1.z = fmaf(A1,w4.z,a1.z); a1.w = fmaf(A1,w4.w,a1.w);
      a2.x = fmaf(A2,w4.x,a2.x); a2.y = fmaf(A2,w4.y,a2.y); a2.z = fmaf(A2,w4.z,a2.z); a2.w = fmaf(A2,w4.w,a2.w);
      a3.x = fmaf(A3,w4.x,a3.x); a3.y = fmaf(A3,w4.y,a3.y); a3.z = fmaf(A3,w4.z,a3.z); a3.w = fmaf(A3,w4.w,a3.w);
    }
    float4 accs[4] = {a0,a1,a2,a3};
    #pragma unroll
    for (int i = 0; i < 4; ++i){
      int m = m0 + ch*32 + ty + 8*i;
      *(float4*)&out[(size_t)m*HH + d0] = accs[i];
    }
    __syncthreads();
  }
}

// ---------------- phase D: DATAFLOW-sync 2D weight-stationary MI-LSTM scan ----------------
// No global barriers. Producer-specific flags:
//   flag_g[bk]: G-block (rg,cg) finished act stores for step t -> value t+1.
//   flag_p[b]:  P-block b finished h/c stores for step t -> value t+1.
// G(t) waits flag_p of its 16 rows >= t; P(t) waits flag_g of its row-group's 23
// blocks >= t+1. Row-groups are fully independent -> no global convergence.
// Buffer-reuse safety: G(t+1) overwrites act only after flag_p >= t+1 (P consumed);
// P(t+1) overwrites h only after all its rg's G set flag_g >= t+2 (done reading h).
__global__ __launch_bounds__(512) void mi_coop(
    const float* __restrict__ ubig,
    const float* __restrict__ xi, const float* __restrict__ xc,
    const float* __restrict__ xf, const float* __restrict__ xo,
    const float* __restrict__ headW, const float* __restrict__ headb,
    float* hR, float* cR,
    float* act, int* flags, float* __restrict__ out)
{
  const int bk = blockIdx.x;
  const int tid = threadIdx.x;
  __shared__ float Wl[128*132];                 // 67.6KB weights [d][c^wkey], persistent
  __shared__ __align__(16) float hLT[128*20];   // 10KB transposed state [d][slot]
  __shared__ __align__(16) float pan[4*2564];   // 41KB partials [dsl][col*20 + rowslot]
  __shared__ float lL[10*128];
  __shared__ float part[8][8];
  __shared__ float uL[10];

  const int rg = bk / 23, cg = bk - rg*23;
  const int rb0 = rg*16;
  int btype; int xk = 0;
  if (cg < 10){ btype = 0; xk = cg; }
  else if (cg < 20){ btype = 1; xk = cg - 10; }
  else if (cg == 20) btype = 2;
  else if (cg == 21) btype = 3;
  else btype = 4;

  // weights: Wl[h*132 + (c ^ wkey(h))], wkey(h) = ((h>>5)&1)<<2
  for (int idx = tid; idx < 128*128; idx += 512){
    int h = idx >> 7, c = idx & 127;
    Wl[h*132 + (c ^ (((h>>5)&1)<<2))] = ubig[(size_t)h*NCOL + cg*128 + c];
  }

  // GEMM thread map (tid<128): dsl = tid&3 (32-d slice), ct = (tid>>2)&15, rt = tid>>6
  const int dsl = tid & 3, ctl = (tid >> 2) & 15, rt = tid >> 6;
  const int c0g = ctl*8;
  const int pkey = (ctl & 3) << 2;              // pan row-slot key (per col>>3)

  // epilogue map (all 512): row erow (0..15), cols ec0..ec0+3
  const int erow = tid >> 5, ec0 = (tid & 31) * 4;
  const float* xrd = nullptr; size_t xrd_step = 0;
  if (btype == 0){ xrd = xi + ((size_t)xk*BB + rb0 + erow)*HH + ec0; xrd_step = (size_t)SS*BB*HH; }
  else if (btype == 1){ xrd = xc + ((size_t)xk*BB + rb0 + erow)*HH + ec0; xrd_step = (size_t)SS*BB*HH; }
  else if (btype == 2){ xrd = xf + (size_t)(rb0 + erow)*HH + ec0; xrd_step = (size_t)BB*HH; }
  else if (btype == 3){ xrd = xo + (size_t)(rb0 + erow)*HH + ec0; xrd_step = (size_t)BB*HH; }

  // P map: 1 row per block (bk<128); wave wv handles stream k = wv (+8 for wv<2)
  const bool isP = (bk < BB);
  const int pb = bk;
  const int rgP = pb >> 4;
  const int wv = tid >> 6, lane = tid & 63;
  float c_reg = 0.f;
  float hw = headW[tid & 127];
  float hb = headb[0];

  int* flag_g = flags;
  int* flag_p = flags + 192;
  const float* arow = act + (size_t)pb*NCOL;   // only dereferenced when isP

  for (int t = 0; t < TT; ++t){
    // ---------- x prefetch (independent of flags) ----------
    float4 xv = make_float4(0.f, 0.f, 0.f, 0.f);
    if (btype != 4) xv = *(const float4*)(xrd + (size_t)t*xrd_step);
    // ---------- WAIT_G: h rows ready (P(t-1) of this block's 16 rows) ----------
    if (tid < 16){
      while (aldi(&flag_p[rb0 + tid]) < t) __builtin_amdgcn_s_sleep(1);
    }
    __syncthreads();
    asm volatile("" ::: "memory");
    // ---------- stage 16 h-rows transposed (1 float4 sc1 load / thread) ----------
    const float* src = (btype == 4) ? cR : hR;
    {
      int bl = tid >> 5;                 // 0..15 local row
      int d4 = (tid & 31) * 4;
      f32x4v sv = ald4(&src[(size_t)(rb0 + bl)*HH + d4]);
      asm volatile("s_waitcnt vmcnt(0)" ::: "memory");
      int slot = bl ^ (((d4 >> 4) & 3) << 2);
      hLT[(d4+0)*20 + slot] = sv.x;
      hLT[(d4+1)*20 + slot] = sv.y;
      hLT[(d4+2)*20 + slot] = sv.z;
      hLT[(d4+3)*20 + slot] = sv.w;
    }
    __syncthreads();
    // ---------- G: 8r x 8c x 32d register-tiled GEMM (tid<128) ----------
    if (tid < 128){
      float acc[8][8];
      #pragma unroll
      for (int i = 0; i < 8; ++i)
        #pragma unroll
        for (int j = 0; j < 8; ++j) acc[i][j] = 0.f;
      const int wkey = (dsl & 1) << 2;
      #pragma unroll 4
      for (int dd = 0; dd < 32; ++dd){
        int d = dsl*32 + dd;
        int akey = ((d >> 4) & 3) << 2;
        float4 a0 = *(const float4*)&hLT[d*20 + ((rt*8)     ^ akey)];
        float4 a1 = *(const float4*)&hLT[d*20 + ((rt*8 + 4) ^ akey)];
        float4 w0 = *(const float4*)&Wl[d*132 + ((c0g)      ^ wkey)];
        float4 w1 = *(const float4*)&Wl[d*132 + ((c0g + 4)  ^ wkey)];
        float a[8] = {a0.x, a0.y, a0.z, a0.w, a1.x, a1.y, a1.z, a1.w};
        float w[8] = {w0.x, w0.y, w0.z, w0.w, w1.x, w1.y, w1.z, w1.w};
        #pragma unroll
        for (int i = 0; i < 8; ++i)
          #pragma unroll
          for (int j = 0; j < 8; ++j)
            acc[i][j] = fmaf(a[i], w[j], acc[i][j]);
      }
      float* pt = pan + dsl*2564;
      #pragma unroll
      for (int j = 0; j < 8; ++j){
        int cb = (c0g + j)*20;
        *(float4*)&pt[cb + ((rt*8)     ^ pkey)] = make_float4(acc[0][j], acc[1][j], acc[2][j], acc[3][j]);
        *(float4*)&pt[cb + ((rt*8 + 4) ^ pkey)] = make_float4(acc[4][j], acc[5][j], acc[6][j], acc[7][j]);
      }
    }
    __syncthreads();
    // ---------- epilogue (512 thr): reduce 4 partials + x + activation + act store ----------
    {
      float xvals[4] = {xv.x, xv.y, xv.z, xv.w};
      float vout[4];
      #pragma unroll
      for (int u = 0; u < 4; ++u){
        int col = ec0 + u;
        int slot = erow ^ (((col >> 3) & 3) << 2);
        int cb = col*20 + slot;
        float pv = pan[cb] + pan[2564 + cb] + pan[2*2564 + cb] + pan[3*2564 + cb] + xvals[u];
        float v;
        if (btype == 1) v = tanhf(pv);
        else if (btype == 4) v = pv;
        else v = sigf(pv);
        vout[u] = v;
      }
      float* ap = &act[(size_t)(rb0 + erow)*NCOL + (size_t)cg*128 + ec0];
      ast4(ap, vout[0], vout[1], vout[2], vout[3]);
    }
    asm volatile("s_waitcnt vmcnt(0)" ::: "memory");
    __syncthreads();
    if (tid == 0) asti(&flag_g[bk], t + 1);
    // ---------- WAIT_P: act row pb ready (23 G-blocks of rgP) ----------
    if (isP && tid < 23){
      while (aldi(&flag_g[rgP*23 + tid]) < t + 1) __builtin_amdgcn_s_sleep(1);
    }
    __syncthreads();
    asm volatile("" ::: "memory");
    // ---------- P: attention + cell update (wave-per-stream u-dots) ----------
    if (isP){
      float cw0 = ald(&arow[2816 + lane]);
      float cw1 = ald(&arow[2816 + lane + 64]);
      #pragma unroll
      for (int kk2 = 0; kk2 < 2; ++kk2){
        if (kk2 == 0 || wv < 2){
          int k = wv + kk2*8;
          float li0 = ald(&arow[k*128 + lane])      * ald(&arow[1280 + k*128 + lane]);
          float li1 = ald(&arow[k*128 + lane + 64]) * ald(&arow[1280 + k*128 + lane + 64]);
          lL[k*128 + lane] = li0;
          lL[k*128 + lane + 64] = li1;
          float s = li0*cw0 + li1*cw1;
          s += __shfl_down(s, 32); s += __shfl_down(s, 16); s += __shfl_down(s, 8);
          s += __shfl_down(s, 4);  s += __shfl_down(s, 2);  s += __shfl_down(s, 1);
          if (lane == 0) uL[k] = tanhf(s);
        }
      }
    }
    __syncthreads();
    if (isP && tid < 128){
      float m = uL[0];
      #pragma unroll
      for (int k = 1; k < 10; ++k) m = fmaxf(m, uL[k]);
      float e[10]; float es = 0.f;
      #pragma unroll
      for (int k = 0; k < 10; ++k){ e[k] = expf(uL[k] - m); es += e[k]; }
      float inv = 1.f / es;
      float lm = 0.f;
      #pragma unroll
      for (int k = 0; k < 10; ++k) lm = fmaf(e[k]*inv, lL[k*128 + tid], lm);
      float f = ald(&arow[2560 + tid]);
      float o = ald(&arow[2688 + tid]);
      float cn = fmaf(f, c_reg, lm);
      float hn = o * tanhf(cn);
      c_reg = cn;
      ast(&hR[pb*HH + tid], hn);
      ast(&cR[pb*HH + tid], cn);
      float s = fmaxf(hn, 0.f) * hw;
      s += __shfl_down(s, 32); s += __shfl_down(s, 16); s += __shfl_down(s, 8);
      s += __shfl_down(s, 4);  s += __shfl_down(s, 2);  s += __shfl_down(s, 1);
      if ((tid & 63) == 0) part[wv][6] = s;
    }
    __syncthreads();
    if (isP && tid == 0)
      out[t*BB + pb] = fmaxf(part[0][6] + part[1][6] + hb, 0.f);
    asm volatile("s_waitcnt vmcnt(0)" ::: "memory");
    __syncthreads();
    if (isP && tid == 0) asti(&flag_p[pb], t + 1);
  }
}

extern "C" void kernel_launch(void* const* d_in, const int* in_sizes, int n_in,
                              void* d_out, int out_size, void* d_ws, size_t ws_size,
                              hipStream_t stream) {
  const float* feat  = (const float*)d_in[0];
  const float* Wih   = (const float*)d_in[1];
  const float* Whh   = (const float*)d_in[2];
  const float* bih   = (const float*)d_in[3];
  const float* bhh   = (const float*)d_in[4];
  const float* miWi  = (const float*)d_in[5];
  const float* miUi  = (const float*)d_in[6];
  const float* mibi  = (const float*)d_in[7];
  const float* miWc  = (const float*)d_in[8];
  const float* miUc  = (const float*)d_in[9];
  const float* mibc  = (const float*)d_in[10];
  const float* miWf  = (const float*)d_in[11];
  const float* miUf  = (const float*)d_in[12];
  const float* mibf  = (const float*)d_in[13];
  const float* miWo  = (const float*)d_in[14];
  const float* miUo  = (const float*)d_in[15];
  const float* mibo  = (const float*)d_in[16];
  const float* miWa  = (const float*)d_in[17];
  const float* headW = (const float*)d_in[18];
  const float* headb = (const float*)d_in[19];
  float* out = (float*)d_out;

  float* ws    = (float*)d_ws;
  float* w2t   = ws + OFF_W2T;
  float* bias2 = ws + OFF_BIAS2;
  float* ubig  = ws + OFF_UBIG;
  float* tilde = ws + OFF_TILDE;
  float* xi    = ws + OFF_XI;
  float* xc    = ws + OFF_XC;
  float* xf    = ws + OFF_XF;
  float* xo    = ws + OFF_XO;
  float* hR    = ws + OFF_HT;
  float* cR    = ws + OFF_CT;
  float* act   = ws + OFF_ACT;
  int*   flags = (int*)(ws + OFF_CNT);

  prep_w2t<<<dim3(SZ_W2T/256), dim3(256), 0, stream>>>(Wih, Whh, bih, bhh, w2t, bias2);
  prep_ubig<<<dim3((SZ_UBIG+255)/256), dim3(256), 0, stream>>>(miUi, miUc, miUf, miUo, miWa, ubig);
  init_state<<<dim3(64), dim3(256), 0, stream>>>(flags, hR, cR);
  lstm_scan<<<dim3(160), dim3(1024), 0, stream>>>(feat, w2t, bias2, tilde);
  proj_ic<<<dim3(256, SS, 2), dim3(256), 0, stream>>>(tilde, miWi, mibi, miWc, mibc, xi, xc);
  proj_fo<<<dim3(256, 2), dim3(256), 0, stream>>>(tilde, miWf, mibf, miWo, mibo, xf, xo);

  void* kargs[] = { (void*)&ubig, (void*)&xi, (void*)&xc, (void*)&xf, (void*)&xo,
                    (void*)&headW, (void*)&headb, (void*)&hR, (void*)&cR,
                    (void*)&act, (void*)&flags, (void*)&out };
  hipLaunchCooperativeKernel((const void*)mi_coop, dim3(NBLK), dim3(512), kargs, 0, stream);
}

// Round 14
// 6337.983 us; speedup vs baseline: 1.5170x; 1.0704x over previous
//
#include <hip/hip_runtime.h>
#include <math.h>

// Model: 10 parallel LSTMs -> MI-LSTM w/ stream attention -> linear head.
// All f32 (no fp32-input MFMA on CDNA4; accuracy threshold requires f32).
//
#define SS 10
#define TT 256
#define BB 128
#define HH 128
#define II 128
#define G4 512     // 4H
#define ZK 256     // I + H (fused [x|h] contraction)
#define NCOL 2944  // phase-D fused weight columns: Ui(1280)|Uc(1280)|Uf(128)|Uo(128)|Wa(128)
#define NBLK 184   // cooperative blocks: 8 row-groups x 23 col-groups (16 rows x 128 cols each)

#define SZ_W2T   (SS*ZK*G4)        // 1,310,720
#define SZ_BIAS2 (SS*G4)           // 5,120
#define SZ_UBIG  (HH*NCOL)         // 376,832
#define SZ_TILDE (SS*TT*BB*HH)     // 41,943,040
#define SZ_X     (TT*SS*BB*HH)     // 41,943,040
#define SZ_XFO   (TT*BB*HH)        // 4,194,304

#define OFF_W2T   0
#define OFF_BIAS2 (OFF_W2T + SZ_W2T)
#define OFF_UBIG  (OFF_BIAS2 + SZ_BIAS2)
#define OFF_TILDE (OFF_UBIG + SZ_UBIG)
#define OFF_XI    (OFF_TILDE + SZ_TILDE)
#define OFF_XC    (OFF_XI + SZ_X)
#define OFF_XF    (OFF_XC + SZ_X)
#define OFF_XO    (OFF_XF + SZ_XFO)
#define OFF_HT    (OFF_XO + SZ_XFO)
#define OFF_CT    (OFF_HT + BB*HH)
#define OFF_ACT   (OFF_CT + BB*HH)
#define OFF_CNT   (OFF_ACT + BB*NCOL)

__device__ __forceinline__ float sigf(float x){ return 1.0f/(1.0f+expf(-x)); }

// per-access coherent ops (sc0/sc1 path; no cache-wide wb/inv)
__device__ __forceinline__ float ald(const float* p){
  return __hip_atomic_load(p, __ATOMIC_RELAXED, __HIP_MEMORY_SCOPE_AGENT);
}
__device__ __forceinline__ void ast(float* p, float v){
  __hip_atomic_store(p, v, __ATOMIC_RELAXED, __HIP_MEMORY_SCOPE_AGENT);
}
__device__ __forceinline__ int aldi(const int* p){
  return __hip_atomic_load(p, __ATOMIC_RELAXED, __HIP_MEMORY_SCOPE_AGENT);
}
__device__ __forceinline__ void asti(int* p, int v){
  __hip_atomic_store(p, v, __ATOMIC_RELAXED, __HIP_MEMORY_SCOPE_AGENT);
}
// 16B coherent ops. ext_vector_type binds to a VGPR quad (HIP float4 is a struct, cannot).
typedef float f32x4v __attribute__((ext_vector_type(4)));
__device__ __forceinline__ void ast4(float* p, float a, float b, float c, float d){
  f32x4v w; w.x = a; w.y = b; w.z = c; w.w = d;
  asm volatile("global_store_dwordx4 %0, %1, off sc0 sc1" :: "v"(p), "v"(w) : "memory");
}
__device__ __forceinline__ f32x4v ald4(const float* p){
  f32x4v r;
  asm volatile("global_load_dwordx4 %0, %1, off sc0 sc1" : "=v"(r) : "v"(p) : "memory");
  return r;
}

// ---------------- prep: fused transposed LSTM weights (b128-friendly) ----------------
__global__ __launch_bounds__(256) void prep_w2t(const float* __restrict__ Wih, const float* __restrict__ Whh,
                                                const float* __restrict__ bih, const float* __restrict__ bhh,
                                                float* __restrict__ w2t, float* __restrict__ bias2){
  int idx = blockIdx.x*256 + threadIdx.x;
  if (idx < SZ_W2T){
    int q = idx & 3; int j = (idx >> 2) & 511; int kk4 = (idx >> 11) & 63; int s = idx >> 17;
    int kk = kk4*4 + q;
    float v = (kk < II) ? Wih[(s*G4 + j)*II + kk] : Whh[(s*G4 + j)*HH + (kk - II)];
    w2t[idx] = v;
  }
  if (idx < SZ_BIAS2) bias2[idx] = bih[idx] + bhh[idx];
}

__global__ __launch_bounds__(256) void prep_ubig(const float* __restrict__ Ui, const float* __restrict__ Uc,
                                                 const float* __restrict__ Uf, const float* __restrict__ Uo,
                                                 const float* __restrict__ Wa, float* __restrict__ ubig){
  int idx = blockIdx.x*256 + threadIdx.x;
  if (idx >= SZ_UBIG) return;
  int col = idx % NCOL; int h = idx / NCOL;
  float v;
  if (col < 1280){ int k = col >> 7, d = col & 127; v = Ui[(k*HH + h)*HH + d]; }
  else if (col < 2560){ int c2 = col - 1280; int k = c2 >> 7, d = c2 & 127; v = Uc[(k*HH + h)*HH + d]; }
  else if (col < 2688){ v = Uf[h*HH + (col - 2560)]; }
  else if (col < 2816){ v = Uo[h*HH + (col - 2688)]; }
  else               { v = Wa[h*HH + (col - 2816)]; }
  ubig[idx] = v;
}

// init: flags + h/c state
__global__ __launch_bounds__(256) void init_state(int* flags, float* hR, float* cR){
  int idx = blockIdx.x*256 + threadIdx.x;
  if (idx < 384) flags[idx] = 0;
  if (idx < BB*HH){ hR[idx] = 0.f; cR[idx] = 0.f; }
}

// ---------------- phase B: fused 10x LSTM scan, split-K, fused activation+update ----------------
// half 0 (tid<512): contract kk 0..127 (x-part); half 1: kk 128..255 (h-part).
// Raw partials -> glp[half]; ONE barrier; update threads (r8,k8) read both
// partials + bias, activate 4 gates inline, cell update, write z. 2 barriers/step.
__global__ __launch_bounds__(1024) void lstm_scan(const float* __restrict__ feat, const float* __restrict__ w2t,
                                                  const float* __restrict__ bias2, float* __restrict__ tilde){
  int p = blockIdx.x;                 // 0..159
  int g = (p & 7) * 20 + (p >> 3);
  int s = g >> 4; int rb = g & 15; int b0 = rb * 8;
  const int tid = threadIdx.x;
  const int j = tid & 511;
  const int half = tid >> 9;
  __shared__ float z[8][ZK];          // 8KB
  __shared__ float glp[2][8][G4];     // 32KB raw partials
  const float* w2ts = w2t + (size_t)s*ZK*G4;
  const float* wb = w2ts + ((size_t)(half*32)*G4 + j)*4;
  const int r8 = tid >> 7;            // 0..7
  const int k8 = tid & 127;
  float b_i = bias2[s*G4 + k8];
  float b_f = bias2[s*G4 + 128 + k8];
  float b_g = bias2[s*G4 + 256 + k8];
  float b_o = bias2[s*G4 + 384 + k8];
  float c = 0.f;
  z[r8][128 + k8] = 0.f;
  z[r8][k8] = feat[((s*TT + 0)*BB + (b0 + r8))*II + k8];
  __syncthreads();
  for (int t = 0; t < TT; ++t){
    float acc[8];
    #pragma unroll
    for (int r=0;r<8;++r) acc[r] = 0.f;
    const float* wp = wb;
    const int kb0 = half*128;
    #pragma unroll 4
    for (int kk4 = 0; kk4 < 32; ++kk4){
      float4 wv = *(const float4*)wp;
      wp += 4*G4;
      #pragma unroll
      for (int r=0;r<8;++r){
        float4 zv = *(const float4*)&z[r][kb0 + kk4*4];
        acc[r] = fmaf(zv.w, wv.w, fmaf(zv.z, wv.z, fmaf(zv.y, wv.y, fmaf(zv.x, wv.x, acc[r]))));
      }
    }
    #pragma unroll
    for (int r=0;r<8;++r) glp[half][r][j] = acc[r];
    __syncthreads();
    {
      float gi = glp[0][r8][k8]       + glp[1][r8][k8]       + b_i;
      float gf = glp[0][r8][128 + k8] + glp[1][r8][128 + k8] + b_f;
      float gg = glp[0][r8][256 + k8] + glp[1][r8][256 + k8] + b_g;
      float go = glp[0][r8][384 + k8] + glp[1][r8][384 + k8] + b_o;
      float i_ = sigf(gi), f_ = sigf(gf), g_ = tanhf(gg), o_ = sigf(go);
      c = f_*c + i_*g_;
      float h = o_*tanhf(c);
      z[r8][128 + k8] = h;
      tilde[((s*TT + t)*BB + (b0 + r8))*HH + k8] = fmaxf(h, 0.f);
      if (t+1 < TT)
        z[r8][k8] = feat[((s*TT + (t+1))*BB + (b0 + r8))*II + k8];
    }
    __syncthreads();
  }
}

// ---------------- phase C: projections (unchanged) ----------------
__global__ __launch_bounds__(256) void proj_ic(const float* __restrict__ tilde,
                                               const float* __restrict__ Wi, const float* __restrict__ bi,
                                               const float* __restrict__ Wc, const float* __restrict__ bc,
                                               float* __restrict__ xi, float* __restrict__ xc){
  const int k = blockIdx.y;
  const int isc = blockIdx.z;
  const float* W = (isc ? Wc : Wi) + k*HH*HH;
  const float* bias = (isc ? bc : bi) + k*HH;
  float* out = isc ? xc : xi;
  const int m0 = blockIdx.x * 128;
  const int tid = threadIdx.x;
  __shared__ float Wl[HH*HH];
  __shared__ float Al[32*HH];
  for (int u = 0; u < 64; ++u) Wl[u*256 + tid] = W[u*256 + tid];
  const int tx = tid & 31, ty = tid >> 5;
  const int d0 = tx*4;
  float4 bv = *(const float4*)&bias[d0];
  __syncthreads();
  for (int ch = 0; ch < 4; ++ch){
    const float* Arow = tilde + (size_t)(k*TT*BB + m0 + ch*32)*HH;
    #pragma unroll
    for (int u = 0; u < 4; ++u)
      *(float4*)&Al[u*1024 + tid*4] = *(const float4*)&Arow[u*1024 + tid*4];
    __syncthreads();
    float4 a0 = bv, a1 = bv, a2 = bv, a3 = bv;
    for (int h = 0; h < HH; ++h){
      float4 w4 = *(const float4*)&Wl[h*HH + d0];
      float A0 = Al[(ty   )*HH + h], A1 = Al[(ty+ 8)*HH + h];
      float A2 = Al[(ty+16)*HH + h], A3 = Al[(ty+24)*HH + h];
      a0.x = fmaf(A0,w4.x,a0.x); a0.y = fmaf(A0,w4.y,a0.y); a0.z = fmaf(A0,w4.z,a0.z); a0.w = fmaf(A0,w4.w,a0.w);
      a1.x = fmaf(A1,w4.x,a1.x); a1.y = fmaf(A1,w4.y,a1.y); a1.z = fmaf(A1,w4.z,a1.z); a1.w = fmaf(A1,w4.w,a1.w);
      a2.x = fmaf(A2,w4.x,a2.x); a2.y = fmaf(A2,w4.y,a2.y); a2.z = fmaf(A2,w4.z,a2.z); a2.w = fmaf(A2,w4.w,a2.w);
      a3.x = fmaf(A3,w4.x,a3.x); a3.y = fmaf(A3,w4.y,a3.y); a3.z = fmaf(A3,w4.z,a3.z); a3.w = fmaf(A3,w4.w,a3.w);
    }
    float4 accs[4] = {a0,a1,a2,a3};
    #pragma unroll
    for (int i = 0; i < 4; ++i){
      int m = m0 + ch*32 + ty + 8*i;
      int t = m >> 7, b = m & 127;
      *(float4*)&out[((t*SS + k)*BB + b)*HH + d0] = accs[i];
    }
    __syncthreads();
  }
}

__global__ __launch_bounds__(256) void proj_fo(const float* __restrict__ tilde,
                                               const float* __restrict__ Wf, const float* __restrict__ bf,
                                               const float* __restrict__ Wo, const float* __restrict__ bo,
                                               float* __restrict__ xf, float* __restrict__ xo){
  const int iso = blockIdx.y;
  const float* W = iso ? Wo : Wf;
  const float* bias = iso ? bo : bf;
  float* out = iso ? xo : xf;
  const int m0 = blockIdx.x * 128;
  const int tid = threadIdx.x;
  __shared__ float Wl[HH*HH];
  __shared__ float Al[32*HH];
  for (int u = 0; u < 64; ++u) Wl[u*256 + tid] = W[u*256 + tid];
  const int tx = tid & 31, ty = tid >> 5;
  const int d0 = tx*4;
  float4 bv = *(const float4*)&bias[d0];
  __syncthreads();
  for (int ch = 0; ch < 4; ++ch){
    const float* Arow = tilde + (size_t)(m0 + ch*32)*HH;
    #pragma unroll
    for (int u = 0; u < 4; ++u)
      *(float4*)&Al[u*1024 + tid*4] = *(const float4*)&Arow[u*1024 + tid*4];
    __syncthreads();
    float4 a0 = bv, a1 = bv, a2 = bv, a3 = bv;
    for (int h = 0; h < HH; ++h){
      float4 w4 = *(const float4*)&Wl[h*HH + d0];
      float A0 = Al[(ty   )*HH + h], A1 = Al[(ty+ 8)*HH + h];
      float A2 = Al[(ty+16)*HH + h], A3 = Al[(ty+24)*HH + h];
      a0.x = fmaf(A0,w4.x,a0.x); a0.y = fmaf(A0,w4.y,a0.y); a0.z = fmaf(A0,w4.z,a0.z); a0.w = fmaf(A0,w4.w,a0.w);
      a1.x = fmaf(A1,w4.x,a1.x); a1.y = fmaf(A1,w4.y,a1.y); a1.z = fmaf(A1,w4.z,a1.z); a1.w = fmaf(A1,w4.w,a1.w);
      a2.x = fmaf(A2,w4.x,a2.x); a2.y = fmaf(A2,w4.y,a2.y); a2.z = fmaf(A2,w4.z,a2.z); a2.w = fmaf(A2,w4.w,a2.w);
      a3.x = fmaf(A3,w4.x,a3.x); a3.y = fmaf(A3,w4.y,a3.y); a3.z = fmaf(A3,w4.z,a3.z); a3.w = fmaf(A3,w4.w,a3.w);
    }
    float4 accs[4] = {a0,a1,a2,a3};
    #pragma unroll
    for (int i = 0; i < 4; ++i){
      int m = m0 + ch*32 + ty + 8*i;
      *(float4*)&out[(size_t)m*HH + d0] = accs[i];
    }
    __syncthreads();
  }
}

// ---------------- phase D: DATAFLOW-sync 2D weight-stationary MI-LSTM scan ----------------
// Conflict-hardened LDS layouts (all XOR keys/offsets multiples of 4, b128-aligned):
//   Wl:  woff(h) = h*132 + ((h>>5)<<3); column slot c ^ ((c>>3)&3)<<2
//   hLT: hoff(d) = d*20  + ((d>>5)<<3); row slot b ^ ((d>>4)&3)<<2
//   pan: poff(col)= col*20 + ((col>>5)<<3); row slot r ^ ((col>>2)&3)<<2
// GEMM on 256 threads: dsl(4 d-slices) x ctl2(32 col-quads) x rt(2 row-octets).
__global__ __launch_bounds__(512) void mi_coop(
    const float* __restrict__ ubig,
    const float* __restrict__ xi, const float* __restrict__ xc,
    const float* __restrict__ xf, const float* __restrict__ xo,
    const float* __restrict__ headW, const float* __restrict__ headb,
    float* hR, float* cR,
    float* act, int* flags, float* __restrict__ out)
{
  const int bk = blockIdx.x;
  const int tid = threadIdx.x;
  __shared__ float Wl[16928];                   // 67.7KB weights, persistent
  __shared__ __align__(16) float hLT[2584];     // 10.3KB transposed state
  __shared__ __align__(16) float pan[4*2584];   // 41.3KB partials
  __shared__ float lL[10*128];
  __shared__ float part[8][8];
  __shared__ float uL[10];

  const int rg = bk / 23, cg = bk - rg*23;
  const int rb0 = rg*16;
  int btype; int xk = 0;
  if (cg < 10){ btype = 0; xk = cg; }
  else if (cg < 20){ btype = 1; xk = cg - 10; }
  else if (cg == 20) btype = 2;
  else if (cg == 21) btype = 3;
  else btype = 4;

  // weights
  for (int idx = tid; idx < 128*128; idx += 512){
    int h = idx >> 7, c = idx & 127;
    Wl[h*132 + ((h>>5)<<3) + (c ^ (((c>>3)&3)<<2))] = ubig[(size_t)h*NCOL + cg*128 + c];
  }

  // GEMM thread map (tid<256)
  const int dsl = tid & 3, ctl2 = (tid >> 2) & 31, rt = (tid >> 7) & 1;
  const int c0g = ctl2*4;
  const int keyc = ((ctl2 >> 1) & 3) << 2;
  const int pkey2 = (ctl2 & 3) << 2;

  // epilogue map (all 512): row erow (0..15), cols ec0..ec0+3
  const int erow = tid >> 5, ec0 = (tid & 31) * 4;
  const float* xrd = nullptr; size_t xrd_step = 0;
  if (btype == 0){ xrd = xi + ((size_t)xk*BB + rb0 + erow)*HH + ec0; xrd_step = (size_t)SS*BB*HH; }
  else if (btype == 1){ xrd = xc + ((size_t)xk*BB + rb0 + erow)*HH + ec0; xrd_step = (size_t)SS*BB*HH; }
  else if (btype == 2){ xrd = xf + (size_t)(rb0 + erow)*HH + ec0; xrd_step = (size_t)BB*HH; }
  else if (btype == 3){ xrd = xo + (size_t)(rb0 + erow)*HH + ec0; xrd_step = (size_t)BB*HH; }

  // P map: 1 row per block (bk<128); wave wv handles stream k = wv (+8 for wv<2)
  const bool isP = (bk < BB);
  const int pb = bk;
  const int rgP = pb >> 4;
  const int wv = tid >> 6, lane = tid & 63;
  float c_reg = 0.f;
  float hw = headW[tid & 127];
  float hb = headb[0];

  int* flag_g = flags;
  int* flag_p = flags + 192;
  const float* arow = act + (size_t)pb*NCOL;   // only dereferenced when isP

  for (int t = 0; t < TT; ++t){
    // ---------- x prefetch (independent of flags) ----------
    float4 xv = make_float4(0.f, 0.f, 0.f, 0.f);
    if (btype != 4) xv = *(const float4*)(xrd + (size_t)t*xrd_step);
    // ---------- WAIT_G: h rows ready ----------
    if (tid < 16){
      while (aldi(&flag_p[rb0 + tid]) < t) __builtin_amdgcn_s_sleep(1);
    }
    __syncthreads();
    asm volatile("" ::: "memory");
    // ---------- stage 16 h-rows transposed ----------
    const float* src = (btype == 4) ? cR : hR;
    {
      int bl = tid >> 5;                 // 0..15 local row
      int d4 = (tid & 31) * 4;
      f32x4v sv = ald4(&src[(size_t)(rb0 + bl)*HH + d4]);
      asm volatile("s_waitcnt vmcnt(0)" ::: "memory");
      int base = d4*20 + ((d4>>5)<<3);
      int slot = bl ^ (((d4 >> 4) & 3) << 2);
      hLT[base + slot]      = sv.x;
      hLT[base + 20 + slot] = sv.y;
      hLT[base + 40 + slot] = sv.z;
      hLT[base + 60 + slot] = sv.w;
    }
    __syncthreads();
    // ---------- G: 8r x 4c x 32d register-tiled GEMM (tid<256, 4 waves) ----------
    if (tid < 256){
      float acc[8][4];
      #pragma unroll
      for (int i = 0; i < 8; ++i)
        #pragma unroll
        for (int j = 0; j < 4; ++j) acc[i][j] = 0.f;
      #pragma unroll 4
      for (int dd = 0; dd < 32; ++dd){
        int d = (dsl << 5) + dd;
        int akey = ((d >> 4) & 3) << 2;
        int hb2 = d*20 + (dsl << 3);
        float4 a0 = *(const float4*)&hLT[hb2 + ((rt*8)     ^ akey)];
        float4 a1 = *(const float4*)&hLT[hb2 + ((rt*8 + 4) ^ akey)];
        float4 w4 = *(const float4*)&Wl[d*132 + (dsl << 3) + (c0g ^ keyc)];
        float a[8] = {a0.x, a0.y, a0.z, a0.w, a1.x, a1.y, a1.z, a1.w};
        float w[4] = {w4.x, w4.y, w4.z, w4.w};
        #pragma unroll
        for (int i = 0; i < 8; ++i)
          #pragma unroll
          for (int j = 0; j < 4; ++j)
            acc[i][j] = fmaf(a[i], w[j], acc[i][j]);
      }
      float* pt = pan + dsl*2584;
      #pragma unroll
      for (int j = 0; j < 4; ++j){
        int col = c0g + j;
        int cb = col*20 + ((col>>5)<<3);
        *(float4*)&pt[cb + ((rt*8)     ^ pkey2)] = make_float4(acc[0][j], acc[1][j], acc[2][j], acc[3][j]);
        *(float4*)&pt[cb + ((rt*8 + 4) ^ pkey2)] = make_float4(acc[4][j], acc[5][j], acc[6][j], acc[7][j]);
      }
    }
    __syncthreads();
    // ---------- epilogue (512 thr): reduce 4 partials + x + activation + act store ----------
    {
      float xvals[4] = {xv.x, xv.y, xv.z, xv.w};
      float vout[4];
      #pragma unroll
      for (int u = 0; u < 4; ++u){
        int col = ec0 + u;
        int slot = erow ^ (((col >> 2) & 3) << 2);
        int cb = col*20 + ((col>>5)<<3) + slot;
        float pv = pan[cb] + pan[2584 + cb] + pan[2*2584 + cb] + pan[3*2584 + cb] + xvals[u];
        float v;
        if (btype == 1) v = tanhf(pv);
        else if (btype == 4) v = pv;
        else v = sigf(pv);
        vout[u] = v;
      }
      float* ap = &act[(size_t)(rb0 + erow)*NCOL + (size_t)cg*128 + ec0];
      ast4(ap, vout[0], vout[1], vout[2], vout[3]);
    }
    asm volatile("s_waitcnt vmcnt(0)" ::: "memory");
    __syncthreads();
    if (tid == 0) asti(&flag_g[bk], t + 1);
    // ---------- WAIT_P: act row pb ready (23 G-blocks of rgP) ----------
    if (isP && tid < 23){
      while (aldi(&flag_g[rgP*23 + tid]) < t + 1) __builtin_amdgcn_s_sleep(1);
    }
    __syncthreads();
    asm volatile("" ::: "memory");
    // ---------- P: attention + cell update (wave-per-stream u-dots) ----------
    if (isP){
      float cw0 = ald(&arow[2816 + lane]);
      float cw1 = ald(&arow[2816 + lane + 64]);
      #pragma unroll
      for (int kk2 = 0; kk2 < 2; ++kk2){
        if (kk2 == 0 || wv < 2){
          int k = wv + kk2*8;
          float li0 = ald(&arow[k*128 + lane])      * ald(&arow[1280 + k*128 + lane]);
          float li1 = ald(&arow[k*128 + lane + 64]) * ald(&arow[1280 + k*128 + lane + 64]);
          lL[k*128 + lane] = li0;
          lL[k*128 + lane + 64] = li1;
          float s = li0*cw0 + li1*cw1;
          s += __shfl_down(s, 32); s += __shfl_down(s, 16); s += __shfl_down(s, 8);
          s += __shfl_down(s, 4);  s += __shfl_down(s, 2);  s += __shfl_down(s, 1);
          if (lane == 0) uL[k] = tanhf(s);
        }
      }
    }
    __syncthreads();
    if (isP && tid < 128){
      float m = uL[0];
      #pragma unroll
      for (int k = 1; k < 10; ++k) m = fmaxf(m, uL[k]);
      float e[10]; float es = 0.f;
      #pragma unroll
      for (int k = 0; k < 10; ++k){ e[k] = expf(uL[k] - m); es += e[k]; }
      float inv = 1.f / es;
      float lm = 0.f;
      #pragma unroll
      for (int k = 0; k < 10; ++k) lm = fmaf(e[k]*inv, lL[k*128 + tid], lm);
      float f = ald(&arow[2560 + tid]);
      float o = ald(&arow[2688 + tid]);
      float cn = fmaf(f, c_reg, lm);
      float hn = o * tanhf(cn);
      c_reg = cn;
      ast(&hR[pb*HH + tid], hn);
      ast(&cR[pb*HH + tid], cn);
      float s = fmaxf(hn, 0.f) * hw;
      s += __shfl_down(s, 32); s += __shfl_down(s, 16); s += __shfl_down(s, 8);
      s += __shfl_down(s, 4);  s += __shfl_down(s, 2);  s += __shfl_down(s, 1);
      if ((tid & 63) == 0) part[wv][6] = s;
    }
    __syncthreads();
    if (isP && tid == 0)
      out[t*BB + pb] = fmaxf(part[0][6] + part[1][6] + hb, 0.f);
    asm volatile("s_waitcnt vmcnt(0)" ::: "memory");
    __syncthreads();
    if (isP && tid == 0) asti(&flag_p[pb], t + 1);
  }
}

extern "C" void kernel_launch(void* const* d_in, const int* in_sizes, int n_in,
                              void* d_out, int out_size, void* d_ws, size_t ws_size,
                              hipStream_t stream) {
  const float* feat  = (const float*)d_in[0];
  const float* Wih   = (const float*)d_in[1];
  const float* Whh   = (const float*)d_in[2];
  const float* bih   = (const float*)d_in[3];
  const float* bhh   = (const float*)d_in[4];
  const float* miWi  = (const float*)d_in[5];
  const float* miUi  = (const float*)d_in[6];
  const float* mibi  = (const float*)d_in[7];
  const float* miWc  = (const float*)d_in[8];
  const float* miUc  = (const float*)d_in[9];
  const float* mibc  = (const float*)d_in[10];
  const float* miWf  = (const float*)d_in[11];
  const float* miUf  = (const float*)d_in[12];
  const float* mibf  = (const float*)d_in[13];
  const float* miWo  = (const float*)d_in[14];
  const float* miUo  = (const float*)d_in[15];
  const float* mibo  = (const float*)d_in[16];
  const float* miWa  = (const float*)d_in[17];
  const float* headW = (const float*)d_in[18];
  const float* headb = (const float*)d_in[19];
  float* out = (float*)d_out;

  float* ws    = (float*)d_ws;
  float* w2t   = ws + OFF_W2T;
  float* bias2 = ws + OFF_BIAS2;
  float* ubig  = ws + OFF_UBIG;
  float* tilde = ws + OFF_TILDE;
  float* xi    = ws + OFF_XI;
  float* xc    = ws + OFF_XC;
  float* xf    = ws + OFF_XF;
  float* xo    = ws + OFF_XO;
  float* hR    = ws + OFF_HT;
  float* cR    = ws + OFF_CT;
  float* act   = ws + OFF_ACT;
  int*   flags = (int*)(ws + OFF_CNT);

  prep_w2t<<<dim3(SZ_W2T/256), dim3(256), 0, stream>>>(Wih, Whh, bih, bhh, w2t, bias2);
  prep_ubig<<<dim3((SZ_UBIG+255)/256), dim3(256), 0, stream>>>(miUi, miUc, miUf, miUo, miWa, ubig);
  init_state<<<dim3(64), dim3(256), 0, stream>>>(flags, hR, cR);
  lstm_scan<<<dim3(160), dim3(1024), 0, stream>>>(feat, w2t, bias2, tilde);
  proj_ic<<<dim3(256, SS, 2), dim3(256), 0, stream>>>(tilde, miWi, mibi, miWc, mibc, xi, xc);
  proj_fo<<<dim3(256, 2), dim3(256), 0, stream>>>(tilde, miWf, mibf, miWo, mibo, xf, xo);

  void* kargs[] = { (void*)&ubig, (void*)&xi, (void*)&xc, (void*)&xf, (void*)&xo,
                    (void*)&headW, (void*)&headb, (void*)&hR, (void*)&cR,
                    (void*)&act, (void*)&flags, (void*)&out };
  hipLaunchCooperativeKernel((const void*)mi_coop, dim3(NBLK), dim3(512), kargs, 0, stream);
}

// Round 15
// 5759.717 us; speedup vs baseline: 1.6693x; 1.1004x over previous
//
#include <hip/hip_runtime.h>
#include <math.h>

// Model: 10 parallel LSTMs -> MI-LSTM w/ stream attention -> linear head.
// All f32 (no fp32-input MFMA on CDNA4; accuracy threshold requires f32).
//
#define SS 10
#define TT 256
#define BB 128
#define HH 128
#define II 128
#define G4 512     // 4H
#define ZK 256     // I + H (fused [x|h] contraction)
#define NCOL 2944  // phase-D fused weight columns: Ui(1280)|Uc(1280)|Uf(128)|Uo(128)|Wa(128)
#define NBLK 184   // cooperative blocks: 8 row-groups x 23 col-groups (16 rows x 128 cols each)

#define SZ_W2T   (SS*ZK*G4)        // 1,310,720
#define SZ_BIAS2 (SS*G4)           // 5,120
#define SZ_UBIG  (HH*NCOL)         // 376,832
#define SZ_TILDE (SS*TT*BB*HH)     // 41,943,040
#define SZ_X     (TT*SS*BB*HH)     // 41,943,040
#define SZ_XFO   (TT*BB*HH)        // 4,194,304

#define OFF_W2T   0
#define OFF_BIAS2 (OFF_W2T + SZ_W2T)
#define OFF_UBIG  (OFF_BIAS2 + SZ_BIAS2)
#define OFF_TILDE (OFF_UBIG + SZ_UBIG)
#define OFF_XI    (OFF_TILDE + SZ_TILDE)
#define OFF_XC    (OFF_XI + SZ_X)
#define OFF_XF    (OFF_XC + SZ_X)
#define OFF_XO    (OFF_XF + SZ_XFO)
#define OFF_HT    (OFF_XO + SZ_XFO)
#define OFF_CT    (OFF_HT + BB*HH)
#define OFF_ACT   (OFF_CT + BB*HH)
#define OFF_CNT   (OFF_ACT + BB*NCOL)

__device__ __forceinline__ float sigf(float x){ return 1.0f/(1.0f+expf(-x)); }

// per-access coherent ops (sc0/sc1 path; no cache-wide wb/inv)
__device__ __forceinline__ float ald(const float* p){
  return __hip_atomic_load(p, __ATOMIC_RELAXED, __HIP_MEMORY_SCOPE_AGENT);
}
__device__ __forceinline__ void ast(float* p, float v){
  __hip_atomic_store(p, v, __ATOMIC_RELAXED, __HIP_MEMORY_SCOPE_AGENT);
}
__device__ __forceinline__ int aldi(const int* p){
  return __hip_atomic_load(p, __ATOMIC_RELAXED, __HIP_MEMORY_SCOPE_AGENT);
}
__device__ __forceinline__ void asti(int* p, int v){
  __hip_atomic_store(p, v, __ATOMIC_RELAXED, __HIP_MEMORY_SCOPE_AGENT);
}
// 16B coherent ops. ext_vector_type binds to a VGPR quad (HIP float4 is a struct, cannot).
typedef float f32x4v __attribute__((ext_vector_type(4)));
__device__ __forceinline__ void ast4(float* p, float a, float b, float c, float d){
  f32x4v w; w.x = a; w.y = b; w.z = c; w.w = d;
  asm volatile("global_store_dwordx4 %0, %1, off sc0 sc1" :: "v"(p), "v"(w) : "memory");
}
__device__ __forceinline__ f32x4v ald4(const float* p){
  f32x4v r;
  asm volatile("global_load_dwordx4 %0, %1, off sc0 sc1" : "=v"(r) : "v"(p) : "memory");
  return r;
}

// ---------------- prep: fused transposed LSTM weights (b128-friendly) ----------------
__global__ __launch_bounds__(256) void prep_w2t(const float* __restrict__ Wih, const float* __restrict__ Whh,
                                                const float* __restrict__ bih, const float* __restrict__ bhh,
                                                float* __restrict__ w2t, float* __restrict__ bias2){
  int idx = blockIdx.x*256 + threadIdx.x;
  if (idx < SZ_W2T){
    int q = idx & 3; int j = (idx >> 2) & 511; int kk4 = (idx >> 11) & 63; int s = idx >> 17;
    int kk = kk4*4 + q;
    float v = (kk < II) ? Wih[(s*G4 + j)*II + kk] : Whh[(s*G4 + j)*HH + (kk - II)];
    w2t[idx] = v;
  }
  if (idx < SZ_BIAS2) bias2[idx] = bih[idx] + bhh[idx];
}

__global__ __launch_bounds__(256) void prep_ubig(const float* __restrict__ Ui, const float* __restrict__ Uc,
                                                 const float* __restrict__ Uf, const float* __restrict__ Uo,
                                                 const float* __restrict__ Wa, float* __restrict__ ubig){
  int idx = blockIdx.x*256 + threadIdx.x;
  if (idx >= SZ_UBIG) return;
  int col = idx % NCOL; int h = idx / NCOL;
  float v;
  if (col < 1280){ int k = col >> 7, d = col & 127; v = Ui[(k*HH + h)*HH + d]; }
  else if (col < 2560){ int c2 = col - 1280; int k = c2 >> 7, d = c2 & 127; v = Uc[(k*HH + h)*HH + d]; }
  else if (col < 2688){ v = Uf[h*HH + (col - 2560)]; }
  else if (col < 2816){ v = Uo[h*HH + (col - 2688)]; }
  else               { v = Wa[h*HH + (col - 2816)]; }
  ubig[idx] = v;
}

// init: flags + h/c state
__global__ __launch_bounds__(256) void init_state(int* flags, float* hR, float* cR){
  int idx = blockIdx.x*256 + threadIdx.x;
  if (idx < 384) flags[idx] = 0;
  if (idx < BB*HH){ hR[idx] = 0.f; cR[idx] = 0.f; }
}

// ---------------- phase B: fused 10x LSTM scan, 4-way split-K, 2 cols/thread ----------------
// Thread (q = tid>>8, j2 = tid&255) computes cols {j2, j2+256} over contraction
// [q*64, q*64+64) for all 8 rows -> 128 z-broadcasts/wave/step (was 256), same FMA.
// glp[4][8][512] partials; update threads sum 4 quarters + bias, activate, update.
__global__ __launch_bounds__(1024) void lstm_scan(const float* __restrict__ feat, const float* __restrict__ w2t,
                                                  const float* __restrict__ bias2, float* __restrict__ tilde){
  int p = blockIdx.x;                 // 0..159
  int g = (p & 7) * 20 + (p >> 3);
  int s = g >> 4; int rb = g & 15; int b0 = rb * 8;
  const int tid = threadIdx.x;
  const int q = tid >> 8;             // 0..3 K-quarter
  const int j2 = tid & 255;           // col pair base
  __shared__ float z[8][ZK];          // 8KB
  __shared__ float glp[4][8][G4];     // 64KB raw partials
  const float* w2ts = w2t + (size_t)s*ZK*G4;
  // per-iter weight base: float4 index (q*16+it)*512 + j2
  const float* wb = w2ts + ((size_t)(q*16)*G4 + j2)*4;
  const int r8 = tid >> 7;            // 0..7 (update row)
  const int k8 = tid & 127;
  float b_i = bias2[s*G4 + k8];
  float b_f = bias2[s*G4 + 128 + k8];
  float b_g = bias2[s*G4 + 256 + k8];
  float b_o = bias2[s*G4 + 384 + k8];
  float c = 0.f;
  z[r8][128 + k8] = 0.f;
  z[r8][k8] = feat[((s*TT + 0)*BB + (b0 + r8))*II + k8];
  __syncthreads();
  for (int t = 0; t < TT; ++t){
    float acc0[8], acc1[8];
    #pragma unroll
    for (int r=0;r<8;++r){ acc0[r] = 0.f; acc1[r] = 0.f; }
    const float* wp = wb;
    const int kb0 = q*64;
    #pragma unroll 4
    for (int it = 0; it < 16; ++it){
      float4 wv0 = *(const float4*)wp;
      float4 wv1 = *(const float4*)(wp + 1024);
      wp += 4*G4;
      #pragma unroll
      for (int r=0;r<8;++r){
        float4 zv = *(const float4*)&z[r][kb0 + it*4];
        acc0[r] = fmaf(zv.w, wv0.w, fmaf(zv.z, wv0.z, fmaf(zv.y, wv0.y, fmaf(zv.x, wv0.x, acc0[r]))));
        acc1[r] = fmaf(zv.w, wv1.w, fmaf(zv.z, wv1.z, fmaf(zv.y, wv1.y, fmaf(zv.x, wv1.x, acc1[r]))));
      }
    }
    #pragma unroll
    for (int r=0;r<8;++r){
      glp[q][r][j2] = acc0[r];
      glp[q][r][j2 + 256] = acc1[r];
    }
    __syncthreads();
    {
      float gi = glp[0][r8][k8]       + glp[1][r8][k8]       + glp[2][r8][k8]       + glp[3][r8][k8]       + b_i;
      float gf = glp[0][r8][128 + k8] + glp[1][r8][128 + k8] + glp[2][r8][128 + k8] + glp[3][r8][128 + k8] + b_f;
      float gg = glp[0][r8][256 + k8] + glp[1][r8][256 + k8] + glp[2][r8][256 + k8] + glp[3][r8][256 + k8] + b_g;
      float go = glp[0][r8][384 + k8] + glp[1][r8][384 + k8] + glp[2][r8][384 + k8] + glp[3][r8][384 + k8] + b_o;
      float i_ = sigf(gi), f_ = sigf(gf), g_ = tanhf(gg), o_ = sigf(go);
      c = f_*c + i_*g_;
      float h = o_*tanhf(c);
      z[r8][128 + k8] = h;
      tilde[((s*TT + t)*BB + (b0 + r8))*HH + k8] = fmaxf(h, 0.f);
      if (t+1 < TT)
        z[r8][k8] = feat[((s*TT + (t+1))*BB + (b0 + r8))*II + k8];
    }
    __syncthreads();
  }
}

// ---------------- phase C: projections (unchanged) ----------------
__global__ __launch_bounds__(256) void proj_ic(const float* __restrict__ tilde,
                                               const float* __restrict__ Wi, const float* __restrict__ bi,
                                               const float* __restrict__ Wc, const float* __restrict__ bc,
                                               float* __restrict__ xi, float* __restrict__ xc){
  const int k = blockIdx.y;
  const int isc = blockIdx.z;
  const float* W = (isc ? Wc : Wi) + k*HH*HH;
  const float* bias = (isc ? bc : bi) + k*HH;
  float* out = isc ? xc : xi;
  const int m0 = blockIdx.x * 128;
  const int tid = threadIdx.x;
  __shared__ float Wl[HH*HH];
  __shared__ float Al[32*HH];
  for (int u = 0; u < 64; ++u) Wl[u*256 + tid] = W[u*256 + tid];
  const int tx = tid & 31, ty = tid >> 5;
  const int d0 = tx*4;
  float4 bv = *(const float4*)&bias[d0];
  __syncthreads();
  for (int ch = 0; ch < 4; ++ch){
    const float* Arow = tilde + (size_t)(k*TT*BB + m0 + ch*32)*HH;
    #pragma unroll
    for (int u = 0; u < 4; ++u)
      *(float4*)&Al[u*1024 + tid*4] = *(const float4*)&Arow[u*1024 + tid*4];
    __syncthreads();
    float4 a0 = bv, a1 = bv, a2 = bv, a3 = bv;
    for (int h = 0; h < HH; ++h){
      float4 w4 = *(const float4*)&Wl[h*HH + d0];
      float A0 = Al[(ty   )*HH + h], A1 = Al[(ty+ 8)*HH + h];
      float A2 = Al[(ty+16)*HH + h], A3 = Al[(ty+24)*HH + h];
      a0.x = fmaf(A0,w4.x,a0.x); a0.y = fmaf(A0,w4.y,a0.y); a0.z = fmaf(A0,w4.z,a0.z); a0.w = fmaf(A0,w4.w,a0.w);
      a1.x = fmaf(A1,w4.x,a1.x); a1.y = fmaf(A1,w4.y,a1.y); a1.z = fmaf(A1,w4.z,a1.z); a1.w = fmaf(A1,w4.w,a1.w);
      a2.x = fmaf(A2,w4.x,a2.x); a2.y = fmaf(A2,w4.y,a2.y); a2.z = fmaf(A2,w4.z,a2.z); a2.w = fmaf(A2,w4.w,a2.w);
      a3.x = fmaf(A3,w4.x,a3.x); a3.y = fmaf(A3,w4.y,a3.y); a3.z = fmaf(A3,w4.z,a3.z); a3.w = fmaf(A3,w4.w,a3.w);
    }
    float4 accs[4] = {a0,a1,a2,a3};
    #pragma unroll
    for (int i = 0; i < 4; ++i){
      int m = m0 + ch*32 + ty + 8*i;
      int t = m >> 7, b = m & 127;
      *(float4*)&out[((t*SS + k)*BB + b)*HH + d0] = accs[i];
    }
    __syncthreads();
  }
}

__global__ __launch_bounds__(256) void proj_fo(const float* __restrict__ tilde,
                                               const float* __restrict__ Wf, const float* __restrict__ bf,
                                               const float* __restrict__ Wo, const float* __restrict__ bo,
                                               float* __restrict__ xf, float* __restrict__ xo){
  const int iso = blockIdx.y;
  const float* W = iso ? Wo : Wf;
  const float* bias = iso ? bo : bf;
  float* out = iso ? xo : xf;
  const int m0 = blockIdx.x * 128;
  const int tid = threadIdx.x;
  __shared__ float Wl[HH*HH];
  __shared__ float Al[32*HH];
  for (int u = 0; u < 64; ++u) Wl[u*256 + tid] = W[u*256 + tid];
  const int tx = tid & 31, ty = tid >> 5;
  const int d0 = tx*4;
  float4 bv = *(const float4*)&bias[d0];
  __syncthreads();
  for (int ch = 0; ch < 4; ++ch){
    const float* Arow = tilde + (size_t)(m0 + ch*32)*HH;
    #pragma unroll
    for (int u = 0; u < 4; ++u)
      *(float4*)&Al[u*1024 + tid*4] = *(const float4*)&Arow[u*1024 + tid*4];
    __syncthreads();
    float4 a0 = bv, a1 = bv, a2 = bv, a3 = bv;
    for (int h = 0; h < HH; ++h){
      float4 w4 = *(const float4*)&Wl[h*HH + d0];
      float A0 = Al[(ty   )*HH + h], A1 = Al[(ty+ 8)*HH + h];
      float A2 = Al[(ty+16)*HH + h], A3 = Al[(ty+24)*HH + h];
      a0.x = fmaf(A0,w4.x,a0.x); a0.y = fmaf(A0,w4.y,a0.y); a0.z = fmaf(A0,w4.z,a0.z); a0.w = fmaf(A0,w4.w,a0.w);
      a1.x = fmaf(A1,w4.x,a1.x); a1.y = fmaf(A1,w4.y,a1.y); a1.z = fmaf(A1,w4.z,a1.z); a1.w = fmaf(A1,w4.w,a1.w);
      a2.x = fmaf(A2,w4.x,a2.x); a2.y = fmaf(A2,w4.y,a2.y); a2.z = fmaf(A2,w4.z,a2.z); a2.w = fmaf(A2,w4.w,a2.w);
      a3.x = fmaf(A3,w4.x,a3.x); a3.y = fmaf(A3,w4.y,a3.y); a3.z = fmaf(A3,w4.z,a3.z); a3.w = fmaf(A3,w4.w,a3.w);
    }
    float4 accs[4] = {a0,a1,a2,a3};
    #pragma unroll
    for (int i = 0; i < 4; ++i){
      int m = m0 + ch*32 + ty + 8*i;
      *(float4*)&out[(size_t)m*HH + d0] = accs[i];
    }
    __syncthreads();
  }
}

// ---------------- phase D: DATAFLOW-sync 2D weight-stationary MI-LSTM scan ----------------
// (unchanged from round 14)
__global__ __launch_bounds__(512) void mi_coop(
    const float* __restrict__ ubig,
    const float* __restrict__ xi, const float* __restrict__ xc,
    const float* __restrict__ xf, const float* __restrict__ xo,
    const float* __restrict__ headW, const float* __restrict__ headb,
    float* hR, float* cR,
    float* act, int* flags, float* __restrict__ out)
{
  const int bk = blockIdx.x;
  const int tid = threadIdx.x;
  __shared__ float Wl[16928];                   // 67.7KB weights, persistent
  __shared__ __align__(16) float hLT[2584];     // 10.3KB transposed state
  __shared__ __align__(16) float pan[4*2584];   // 41.3KB partials
  __shared__ float lL[10*128];
  __shared__ float part[8][8];
  __shared__ float uL[10];

  const int rg = bk / 23, cg = bk - rg*23;
  const int rb0 = rg*16;
  int btype; int xk = 0;
  if (cg < 10){ btype = 0; xk = cg; }
  else if (cg < 20){ btype = 1; xk = cg - 10; }
  else if (cg == 20) btype = 2;
  else if (cg == 21) btype = 3;
  else btype = 4;

  // weights
  for (int idx = tid; idx < 128*128; idx += 512){
    int h = idx >> 7, c = idx & 127;
    Wl[h*132 + ((h>>5)<<3) + (c ^ (((c>>3)&3)<<2))] = ubig[(size_t)h*NCOL + cg*128 + c];
  }

  // GEMM thread map (tid<256)
  const int dsl = tid & 3, ctl2 = (tid >> 2) & 31, rt = (tid >> 7) & 1;
  const int c0g = ctl2*4;
  const int keyc = ((ctl2 >> 1) & 3) << 2;
  const int pkey2 = (ctl2 & 3) << 2;

  // epilogue map (all 512): row erow (0..15), cols ec0..ec0+3
  const int erow = tid >> 5, ec0 = (tid & 31) * 4;
  const float* xrd = nullptr; size_t xrd_step = 0;
  if (btype == 0){ xrd = xi + ((size_t)xk*BB + rb0 + erow)*HH + ec0; xrd_step = (size_t)SS*BB*HH; }
  else if (btype == 1){ xrd = xc + ((size_t)xk*BB + rb0 + erow)*HH + ec0; xrd_step = (size_t)SS*BB*HH; }
  else if (btype == 2){ xrd = xf + (size_t)(rb0 + erow)*HH + ec0; xrd_step = (size_t)BB*HH; }
  else if (btype == 3){ xrd = xo + (size_t)(rb0 + erow)*HH + ec0; xrd_step = (size_t)BB*HH; }

  // P map: 1 row per block (bk<128); wave wv handles stream k = wv (+8 for wv<2)
  const bool isP = (bk < BB);
  const int pb = bk;
  const int rgP = pb >> 4;
  const int wv = tid >> 6, lane = tid & 63;
  float c_reg = 0.f;
  float hw = headW[tid & 127];
  float hb = headb[0];

  int* flag_g = flags;
  int* flag_p = flags + 192;
  const float* arow = act + (size_t)pb*NCOL;   // only dereferenced when isP

  for (int t = 0; t < TT; ++t){
    // ---------- x prefetch (independent of flags) ----------
    float4 xv = make_float4(0.f, 0.f, 0.f, 0.f);
    if (btype != 4) xv = *(const float4*)(xrd + (size_t)t*xrd_step);
    // ---------- WAIT_G: h rows ready ----------
    if (tid < 16){
      while (aldi(&flag_p[rb0 + tid]) < t) __builtin_amdgcn_s_sleep(1);
    }
    __syncthreads();
    asm volatile("" ::: "memory");
    // ---------- stage 16 h-rows transposed ----------
    const float* src = (btype == 4) ? cR : hR;
    {
      int bl = tid >> 5;                 // 0..15 local row
      int d4 = (tid & 31) * 4;
      f32x4v sv = ald4(&src[(size_t)(rb0 + bl)*HH + d4]);
      asm volatile("s_waitcnt vmcnt(0)" ::: "memory");
      int base = d4*20 + ((d4>>5)<<3);
      int slot = bl ^ (((d4 >> 4) & 3) << 2);
      hLT[base + slot]      = sv.x;
      hLT[base + 20 + slot] = sv.y;
      hLT[base + 40 + slot] = sv.z;
      hLT[base + 60 + slot] = sv.w;
    }
    __syncthreads();
    // ---------- G: 8r x 4c x 32d register-tiled GEMM (tid<256, 4 waves) ----------
    if (tid < 256){
      float acc[8][4];
      #pragma unroll
      for (int i = 0; i < 8; ++i)
        #pragma unroll
        for (int j = 0; j < 4; ++j) acc[i][j] = 0.f;
      #pragma unroll 4
      for (int dd = 0; dd < 32; ++dd){
        int d = (dsl << 5) + dd;
        int akey = ((d >> 4) & 3) << 2;
        int hb2 = d*20 + (dsl << 3);
        float4 a0 = *(const float4*)&hLT[hb2 + ((rt*8)     ^ akey)];
        float4 a1 = *(const float4*)&hLT[hb2 + ((rt*8 + 4) ^ akey)];
        float4 w4 = *(const float4*)&Wl[d*132 + (dsl << 3) + (c0g ^ keyc)];
        float a[8] = {a0.x, a0.y, a0.z, a0.w, a1.x, a1.y, a1.z, a1.w};
        float w[4] = {w4.x, w4.y, w4.z, w4.w};
        #pragma unroll
        for (int i = 0; i < 8; ++i)
          #pragma unroll
          for (int j = 0; j < 4; ++j)
            acc[i][j] = fmaf(a[i], w[j], acc[i][j]);
      }
      float* pt = pan + dsl*2584;
      #pragma unroll
      for (int j = 0; j < 4; ++j){
        int col = c0g + j;
        int cb = col*20 + ((col>>5)<<3);
        *(float4*)&pt[cb + ((rt*8)     ^ pkey2)] = make_float4(acc[0][j], acc[1][j], acc[2][j], acc[3][j]);
        *(float4*)&pt[cb + ((rt*8 + 4) ^ pkey2)] = make_float4(acc[4][j], acc[5][j], acc[6][j], acc[7][j]);
      }
    }
    __syncthreads();
    // ---------- epilogue (512 thr): reduce 4 partials + x + activation + act store ----------
    {
      float xvals[4] = {xv.x, xv.y, xv.z, xv.w};
      float vout[4];
      #pragma unroll
      for (int u = 0; u < 4; ++u){
        int col = ec0 + u;
        int slot = erow ^ (((col >> 2) & 3) << 2);
        int cb = col*20 + ((col>>5)<<3) + slot;
        float pv = pan[cb] + pan[2584 + cb] + pan[2*2584 + cb] + pan[3*2584 + cb] + xvals[u];
        float v;
        if (btype == 1) v = tanhf(pv);
        else if (btype == 4) v = pv;
        else v = sigf(pv);
        vout[u] = v;
      }
      float* ap = &act[(size_t)(rb0 + erow)*NCOL + (size_t)cg*128 + ec0];
      ast4(ap, vout[0], vout[1], vout[2], vout[3]);
    }
    asm volatile("s_waitcnt vmcnt(0)" ::: "memory");
    __syncthreads();
    if (tid == 0) asti(&flag_g[bk], t + 1);
    // ---------- WAIT_P: act row pb ready (23 G-blocks of rgP) ----------
    if (isP && tid < 23){
      while (aldi(&flag_g[rgP*23 + tid]) < t + 1) __builtin_amdgcn_s_sleep(1);
    }
    __syncthreads();
    asm volatile("" ::: "memory");
    // ---------- P: attention + cell update (wave-per-stream u-dots) ----------
    if (isP){
      float cw0 = ald(&arow[2816 + lane]);
      float cw1 = ald(&arow[2816 + lane + 64]);
      #pragma unroll
      for (int kk2 = 0; kk2 < 2; ++kk2){
        if (kk2 == 0 || wv < 2){
          int k = wv + kk2*8;
          float li0 = ald(&arow[k*128 + lane])      * ald(&arow[1280 + k*128 + lane]);
          float li1 = ald(&arow[k*128 + lane + 64]) * ald(&arow[1280 + k*128 + lane + 64]);
          lL[k*128 + lane] = li0;
          lL[k*128 + lane + 64] = li1;
          float s = li0*cw0 + li1*cw1;
          s += __shfl_down(s, 32); s += __shfl_down(s, 16); s += __shfl_down(s, 8);
          s += __shfl_down(s, 4);  s += __shfl_down(s, 2);  s += __shfl_down(s, 1);
          if (lane == 0) uL[k] = tanhf(s);
        }
      }
    }
    __syncthreads();
    if (isP && tid < 128){
      float m = uL[0];
      #pragma unroll
      for (int k = 1; k < 10; ++k) m = fmaxf(m, uL[k]);
      float e[10]; float es = 0.f;
      #pragma unroll
      for (int k = 0; k < 10; ++k){ e[k] = expf(uL[k] - m); es += e[k]; }
      float inv = 1.f / es;
      float lm = 0.f;
      #pragma unroll
      for (int k = 0; k < 10; ++k) lm = fmaf(e[k]*inv, lL[k*128 + tid], lm);
      float f = ald(&arow[2560 + tid]);
      float o = ald(&arow[2688 + tid]);
      float cn = fmaf(f, c_reg, lm);
      float hn = o * tanhf(cn);
      c_reg = cn;
      ast(&hR[pb*HH + tid], hn);
      ast(&cR[pb*HH + tid], cn);
      float s = fmaxf(hn, 0.f) * hw;
      s += __shfl_down(s, 32); s += __shfl_down(s, 16); s += __shfl_down(s, 8);
      s += __shfl_down(s, 4);  s += __shfl_down(s, 2);  s += __shfl_down(s, 1);
      if ((tid & 63) == 0) part[wv][6] = s;
    }
    __syncthreads();
    if (isP && tid == 0)
      out[t*BB + pb] = fmaxf(part[0][6] + part[1][6] + hb, 0.f);
    asm volatile("s_waitcnt vmcnt(0)" ::: "memory");
    __syncthreads();
    if (isP && tid == 0) asti(&flag_p[pb], t + 1);
  }
}

extern "C" void kernel_launch(void* const* d_in, const int* in_sizes, int n_in,
                              void* d_out, int out_size, void* d_ws, size_t ws_size,
                              hipStream_t stream) {
  const float* feat  = (const float*)d_in[0];
  const float* Wih   = (const float*)d_in[1];
  const float* Whh   = (const float*)d_in[2];
  const float* bih   = (const float*)d_in[3];
  const float* bhh   = (const float*)d_in[4];
  const float* miWi  = (const float*)d_in[5];
  const float* miUi  = (const float*)d_in[6];
  const float* mibi  = (const float*)d_in[7];
  const float* miWc  = (const float*)d_in[8];
  const float* miUc  = (const float*)d_in[9];
  const float* mibc  = (const float*)d_in[10];
  const float* miWf  = (const float*)d_in[11];
  const float* miUf  = (const float*)d_in[12];
  const float* mibf  = (const float*)d_in[13];
  const float* miWo  = (const float*)d_in[14];
  const float* miUo  = (const float*)d_in[15];
  const float* mibo  = (const float*)d_in[16];
  const float* miWa  = (const float*)d_in[17];
  const float* headW = (const float*)d_in[18];
  const float* headb = (const float*)d_in[19];
  float* out = (float*)d_out;

  float* ws    = (float*)d_ws;
  float* w2t   = ws + OFF_W2T;
  float* bias2 = ws + OFF_BIAS2;
  float* ubig  = ws + OFF_UBIG;
  float* tilde = ws + OFF_TILDE;
  float* xi    = ws + OFF_XI;
  float* xc    = ws + OFF_XC;
  float* xf    = ws + OFF_XF;
  float* xo    = ws + OFF_XO;
  float* hR    = ws + OFF_HT;
  float* cR    = ws + OFF_CT;
  float* act   = ws + OFF_ACT;
  int*   flags = (int*)(ws + OFF_CNT);

  prep_w2t<<<dim3(SZ_W2T/256), dim3(256), 0, stream>>>(Wih, Whh, bih, bhh, w2t, bias2);
  prep_ubig<<<dim3((SZ_UBIG+255)/256), dim3(256), 0, stream>>>(miUi, miUc, miUf, miUo, miWa, ubig);
  init_state<<<dim3(64), dim3(256), 0, stream>>>(flags, hR, cR);
  lstm_scan<<<dim3(160), dim3(1024), 0, stream>>>(feat, w2t, bias2, tilde);
  proj_ic<<<dim3(256, SS, 2), dim3(256), 0, stream>>>(tilde, miWi, mibi, miWc, mibc, xi, xc);
  proj_fo<<<dim3(256, 2), dim3(256), 0, stream>>>(tilde, miWf, mibf, miWo, mibo, xf, xo);

  void* kargs[] = { (void*)&ubig, (void*)&xi, (void*)&xc, (void*)&xf, (void*)&xo,
                    (void*)&headW, (void*)&headb, (void*)&hR, (void*)&cR,
                    (void*)&act, (void*)&flags, (void*)&out };
  hipLaunchCooperativeKernel((const void*)mi_coop, dim3(NBLK), dim3(512), kargs, 0, stream);
}